// Round 1
// baseline (802.017 us; speedup 1.0000x reference)
//
#include <hip/hip_runtime.h>
#include <math.h>

// Problem dims
#define BL    6
#define CCH   64
#define C3    192
#define L2    1024
#define DIC   128
#define NST   16
#define K4    4

#define LOG2E 1.44269504088896340736f
#define LN2C  0.69314718055994530942f

__device__ __forceinline__ float fexp(float x){ return __builtin_amdgcn_exp2f(x*LOG2E); }
__device__ __forceinline__ float fsilu(float x){ return x / (1.f + fexp(-x)); }
__device__ __forceinline__ float fsoftplus(float x){
  if (x > 20.f) return x;
  return __builtin_amdgcn_logf(1.f + fexp(x)) * LN2C;
}
__device__ __forceinline__ float fgelu(float x){
  return 0.5f*x*(1.f + erff(x*0.70710678118654752440f));
}

// ---------------- A: per-pixel channel LayerNorm of frames + concat [dz, frames_n, sigma]
__global__ __launch_bounds__(256) void k_ln2d_concat(const float* __restrict__ img,
    const float* __restrict__ dz, const float* __restrict__ sg,
    const float* __restrict__ g, const float* __restrict__ b, float* __restrict__ x3c){
  int bx = blockIdx.x; int s = bx>>2; int p = ((bx&3)<<8) + threadIdx.x;
  int bsmp = s/3;
  const float* fr = img + s*CCH*L2;
  float sm=0.f, sq=0.f;
  for (int c=0;c<CCH;++c){ float v = fr[c*L2+p]; sm+=v; sq+=v*v; }
  float mean = sm*(1.f/CCH); float var = sq*(1.f/CCH) - mean*mean;
  float rs = rsqrtf(var + 1e-6f);
  float* o = x3c + s*C3*L2;
  const float* dzp = dz + bsmp*CCH*L2;
  const float* sgp = sg + bsmp*CCH*L2;
  for (int c=0;c<CCH;++c){
    o[c*L2+p] = dzp[c*L2+p];
    float v = fr[c*L2+p];
    o[(CCH+c)*L2+p] = (v-mean)*rs*g[c] + b[c];
    o[(2*CCH+c)*L2+p] = sgp[c*L2+p];
  }
}

// ---------------- B/E: GroupNorm(1) stats per sample
__global__ __launch_bounds__(256) void k_gnstats(const float* __restrict__ x, int elems_per_s,
    float* __restrict__ stats, float eps){
  int s = blockIdx.x; int tid = threadIdx.x;
  const float* xs = x + (size_t)s*elems_per_s;
  float sm=0.f, sq=0.f;
  for (int idx = tid*4; idx < elems_per_s; idx += 256*4){
    float4 v = *(const float4*)(xs+idx);
    sm += v.x+v.y+v.z+v.w;
    sq += v.x*v.x+v.y*v.y+v.z*v.z+v.w*v.w;
  }
  for (int m=1;m<64;m<<=1){ sm+=__shfl_xor(sm,m,64); sq+=__shfl_xor(sq,m,64); }
  __shared__ float s_sm[4], s_sq[4];
  int wv = tid>>6;
  if ((tid&63)==0){ s_sm[wv]=sm; s_sq[wv]=sq; }
  __syncthreads();
  if (tid==0){
    float S = s_sm[0]+s_sm[1]+s_sm[2]+s_sm[3];
    float Q = s_sq[0]+s_sq[1]+s_sq[2]+s_sq[3];
    float mean = S/elems_per_s; float var = Q/elems_per_s - mean*mean;
    stats[s*2] = mean; stats[s*2+1] = rsqrtf(var+eps);
  }
}

// ---------------- C/F: apply GN affine + SiLU elementwise (ch = channels per sample)
__global__ __launch_bounds__(256) void k_gnact(const float* __restrict__ x,
    const float* __restrict__ stats, const float* __restrict__ g, const float* __restrict__ b,
    int ch, float* __restrict__ out){
  int bx = blockIdx.x;
  int s = bx / ch; int c = bx % ch;
  float mean = stats[s*2], rs = stats[s*2+1];
  float gc = g[c]*rs; float bc = b[c] - mean*rs*g[c];
  size_t base = (size_t)bx*1024 + threadIdx.x*4;
  float4 v = *(const float4*)(x + base);
  float t0 = v.x*gc+bc, t1 = v.y*gc+bc, t2 = v.z*gc+bc, t3 = v.w*gc+bc;
  float4 o; o.x = fsilu(t0); o.y = fsilu(t1); o.z = fsilu(t2); o.w = fsilu(t3);
  *(float4*)(out + base) = o;
}

// conv row helper: accumulate 3 taps for 2 output channels over a 4-px quad
__device__ __forceinline__ void conv_row_acc(float4& a0, float4& a1, float4 mid, float lf, float rt,
    const float* wp0, const float* wp1){
  float w0=wp0[0], w1=wp0[1], w2=wp0[2];
  a0.x = fmaf(w0,lf,   fmaf(w1,mid.x, fmaf(w2,mid.y, a0.x)));
  a0.y = fmaf(w0,mid.x,fmaf(w1,mid.y, fmaf(w2,mid.z, a0.y)));
  a0.z = fmaf(w0,mid.y,fmaf(w1,mid.z, fmaf(w2,mid.w, a0.z)));
  a0.w = fmaf(w0,mid.z,fmaf(w1,mid.w, fmaf(w2,rt,    a0.w)));
  float v0=wp1[0], v1=wp1[1], v2=wp1[2];
  a1.x = fmaf(v0,lf,   fmaf(v1,mid.x, fmaf(v2,mid.y, a1.x)));
  a1.y = fmaf(v0,mid.x,fmaf(v1,mid.y, fmaf(v2,mid.z, a1.y)));
  a1.z = fmaf(v0,mid.y,fmaf(v1,mid.z, fmaf(v2,mid.w, a1.z)));
  a1.w = fmaf(v0,mid.z,fmaf(v1,mid.w, fmaf(v2,rt,    a1.w)));
}

// ---------------- D: 3x3 conv, CI input ch -> 64 out ch, 2 out ch per block
template<int CI>
__global__ __launch_bounds__(256) void k_conv3x3(const float* __restrict__ xin_,
    const float* __restrict__ w, const float* __restrict__ bias, float* __restrict__ out){
  int bx = blockIdx.x; int cop = bx & 31; int s = bx >> 5;
  int co0 = cop*2, co1 = co0+1;
  int tid = threadIdx.x; int row = tid>>3; int q = tid&7; int col0 = q*4;
  int p = row*32+col0;
  float b0 = bias[co0], b1v = bias[co1];
  float4 a0 = make_float4(b0,b0,b0,b0);
  float4 a1 = make_float4(b1v,b1v,b1v,b1v);
  const float* xin = xin_ + (size_t)s*CI*L2;
  for (int ci=0; ci<CI; ++ci){
    const float* xr = xin + ci*L2;
    const float* wb0 = w + (size_t)(co0*CI + ci)*9;
    const float* wb1 = w + (size_t)(co1*CI + ci)*9;
    #pragma unroll
    for (int dy=-1; dy<=1; ++dy){
      int r = row+dy;
      float4 mid = make_float4(0.f,0.f,0.f,0.f);
      if (0 <= r && r < 32) mid = *(const float4*)(xr + r*32 + col0);
      float lf = __shfl_up(mid.w, 1, 64); if (q==0) lf = 0.f;
      float rt = __shfl_down(mid.x, 1, 64); if (q==7) rt = 0.f;
      conv_row_acc(a0, a1, mid, lf, rt, wb0 + (dy+1)*3, wb1 + (dy+1)*3);
    }
  }
  *(float4*)(out + ((size_t)s*CCH+co0)*L2 + p) = a0;
  *(float4*)(out + ((size_t)s*CCH+co1)*L2 + p) = a1;
}

// ---------------- G: conv2(3x3) + skip(1x1 over x3c) -> x in both layouts
__global__ __launch_bounds__(256) void k_conv2_skip(const float* __restrict__ xact2,
    const float* __restrict__ x3c, const float* __restrict__ w2, const float* __restrict__ b2,
    const float* __restrict__ wsk, const float* __restrict__ bsk,
    float* __restrict__ xp, float* __restrict__ x_cmaj){
  int bx = blockIdx.x; int cop = bx & 31; int s = bx >> 5;
  int co0 = cop*2, co1 = co0+1;
  int tid = threadIdx.x; int row = tid>>3; int q = tid&7; int col0 = q*4;
  int p = row*32+col0;
  float bi0 = b2[co0]+bsk[co0], bi1 = b2[co1]+bsk[co1];
  float4 a0 = make_float4(bi0,bi0,bi0,bi0);
  float4 a1 = make_float4(bi1,bi1,bi1,bi1);
  const float* xin = xact2 + (size_t)s*CCH*L2;
  for (int ci=0; ci<CCH; ++ci){
    const float* xr = xin + ci*L2;
    const float* wb0 = w2 + (size_t)(co0*CCH + ci)*9;
    const float* wb1 = w2 + (size_t)(co1*CCH + ci)*9;
    #pragma unroll
    for (int dy=-1; dy<=1; ++dy){
      int r = row+dy;
      float4 mid = make_float4(0.f,0.f,0.f,0.f);
      if (0 <= r && r < 32) mid = *(const float4*)(xr + r*32 + col0);
      float lf = __shfl_up(mid.w, 1, 64); if (q==0) lf = 0.f;
      float rt = __shfl_down(mid.x, 1, 64); if (q==7) rt = 0.f;
      conv_row_acc(a0, a1, mid, lf, rt, wb0 + (dy+1)*3, wb1 + (dy+1)*3);
    }
  }
  const float* x3 = x3c + (size_t)s*C3*L2 + p;
  for (int ci=0; ci<C3; ++ci){
    float4 v = *(const float4*)(x3 + ci*L2);
    float ws0 = wsk[co0*C3+ci], ws1 = wsk[co1*C3+ci];
    a0.x = fmaf(ws0,v.x,a0.x); a0.y = fmaf(ws0,v.y,a0.y); a0.z = fmaf(ws0,v.z,a0.z); a0.w = fmaf(ws0,v.w,a0.w);
    a1.x = fmaf(ws1,v.x,a1.x); a1.y = fmaf(ws1,v.y,a1.y); a1.z = fmaf(ws1,v.z,a1.z); a1.w = fmaf(ws1,v.w,a1.w);
  }
  *(float4*)(x_cmaj + ((size_t)s*CCH+co0)*L2 + p) = a0;
  *(float4*)(x_cmaj + ((size_t)s*CCH+co1)*L2 + p) = a1;
  float* xpb = xp + ((size_t)s*L2 + p)*CCH;
  xpb[co0] = a0.x; xpb[CCH+co0] = a0.y; xpb[2*CCH+co0] = a0.z; xpb[3*CCH+co0] = a0.w;
  xpb[co1] = a1.x; xpb[CCH+co1] = a1.y; xpb[2*CCH+co1] = a1.z; xpb[3*CCH+co1] = a1.w;
}

// ---------------- H: ln1 + in_proj (256 outputs); split into xc (c-major) and z (c-major)
__global__ __launch_bounds__(256) void k_ln1_inproj(const float* __restrict__ xp,
    const float* __restrict__ g, const float* __restrict__ b, const float* __restrict__ W,
    float* __restrict__ xc, float* __restrict__ z_t){
  __shared__ float xn_s[64*65];
  int s = blockIdx.x >> 4; int p0 = (blockIdx.x & 15)*64;
  int tid = threadIdx.x; int wv = __builtin_amdgcn_readfirstlane(tid>>6); int lane = tid&63;
  for (int j=0;j<16;++j){
    int pl = wv*16 + j; int p = p0 + pl;
    float v = xp[((size_t)s*L2 + p)*CCH + lane];
    float sm = v, sq = v*v;
    for (int m=1;m<64;m<<=1){ sm += __shfl_xor(sm,m,64); sq += __shfl_xor(sq,m,64); }
    float mean = sm*(1.f/64.f); float var = sq*(1.f/64.f) - mean*mean;
    float rs = rsqrtf(var + 1e-5f);
    xn_s[pl*65 + lane] = (v-mean)*rs*g[lane] + b[lane];
  }
  __syncthreads();
  int px_l = tid & 63;
  int og = __builtin_amdgcn_readfirstlane(tid >> 6);
  int o0 = og*64;
  float acc[64];
  #pragma unroll
  for (int oi=0;oi<64;++oi) acc[oi]=0.f;
  for (int c=0;c<64;++c){
    float xv = xn_s[px_l*65 + c];
    #pragma unroll
    for (int oi=0;oi<64;++oi) acc[oi] = fmaf(W[(o0+oi)*64 + c], xv, acc[oi]);
  }
  int p = p0 + px_l;
  if (og < 2){
    #pragma unroll
    for (int oi=0;oi<64;++oi) xc[((size_t)s*DIC + o0 + oi)*L2 + p] = acc[oi];
  } else {
    #pragma unroll
    for (int oi=0;oi<64;++oi) z_t[((size_t)s*DIC + (o0-128) + oi)*L2 + p] = acc[oi];
  }
}

// ---------------- I: depthwise 3x3 conv + bias + SiLU
__global__ __launch_bounds__(256) void k_dwconv(const float* __restrict__ xc,
    const float* __restrict__ w, const float* __restrict__ bias, float* __restrict__ xconv){
  int bx = blockIdx.x; int dch = bx & 127; int s = bx >> 7;
  int tid = threadIdx.x; int row = tid>>3; int q = tid&7; int col0 = q*4;
  const float* xr = xc + ((size_t)s*DIC+dch)*L2;
  const float* wp = w + dch*9;
  float bv = bias[dch];
  float4 acc = make_float4(bv,bv,bv,bv);
  #pragma unroll
  for (int dy=-1;dy<=1;++dy){
    int r = row+dy;
    float4 mid = make_float4(0.f,0.f,0.f,0.f);
    if (0<=r && r<32) mid = *(const float4*)(xr + r*32 + col0);
    float lf = __shfl_up(mid.w,1,64); if(q==0) lf=0.f;
    float rt = __shfl_down(mid.x,1,64); if(q==7) rt=0.f;
    float w0=wp[(dy+1)*3], w1=wp[(dy+1)*3+1], w2=wp[(dy+1)*3+2];
    acc.x = fmaf(w0,lf,   fmaf(w1,mid.x, fmaf(w2,mid.y, acc.x)));
    acc.y = fmaf(w0,mid.x,fmaf(w1,mid.y, fmaf(w2,mid.z, acc.y)));
    acc.z = fmaf(w0,mid.y,fmaf(w1,mid.z, fmaf(w2,mid.w, acc.z)));
    acc.w = fmaf(w0,mid.z,fmaf(w1,mid.w, fmaf(w2,rt,    acc.w)));
  }
  acc.x = fsilu(acc.x); acc.y = fsilu(acc.y); acc.z = fsilu(acc.z); acc.w = fsilu(acc.w);
  *(float4*)(xconv + ((size_t)s*DIC+dch)*L2 + row*32+col0) = acc;
}

// ---------------- J: x_proj: t36[s,k,c,p] = sum_d Xw[k,c,d]*xconv[s,d,p] (pixel order)
__global__ __launch_bounds__(256) void k_xproj(const float* __restrict__ xconv,
    const float* __restrict__ W, float* __restrict__ t36){
  int bx = blockIdx.x;
  int pg = bx & 3; int t = bx >> 2;
  int cg = t % 6; int t2 = t / 6;
  int k = t2 & 3; int s = t2 >> 2;
  int px = pg*256 + threadIdx.x;
  const float* xb = xconv + (size_t)s*DIC*L2 + px;
  const float* wb = W + (size_t)(k*36 + cg*6)*DIC;
  float acc[6] = {0.f,0.f,0.f,0.f,0.f,0.f};
  for (int dch=0; dch<DIC; ++dch){
    float v = xb[(size_t)dch*L2];
    #pragma unroll
    for (int ci=0; ci<6; ++ci) acc[ci] = fmaf(wb[ci*DIC+dch], v, acc[ci]);
  }
  float* ob = t36 + ((size_t)(s*4+k)*36 + cg*6)*L2 + px;
  #pragma unroll
  for (int ci=0;ci<6;++ci) ob[(size_t)ci*L2] = acc[ci];
}

// ---------------- K: dt = softplus(dt_proj(t36[0:4]) + bias), pixel order
__global__ void k_dt(const float* __restrict__ t36, const float* __restrict__ dtw,
    const float* __restrict__ dtb, float* __restrict__ dts){
  int dgrp = blockIdx.x & 31; int k = (blockIdx.x>>5)&3; int s = blockIdx.x>>7;
  int lane = threadIdx.x;
  int dl = __builtin_amdgcn_readfirstlane(threadIdx.y);
  int dch = dgrp*4 + dl;
  const float* tb = t36 + (size_t)(s*4+k)*36*L2;
  float w0 = dtw[(k*DIC+dch)*4+0], w1 = dtw[(k*DIC+dch)*4+1];
  float w2 = dtw[(k*DIC+dch)*4+2], w3 = dtw[(k*DIC+dch)*4+3];
  float bb = dtb[k*DIC+dch];
  float* ob = dts + ((size_t)(s*4+k)*DIC + dch)*L2;
  for (int pg=0; pg<4; ++pg){
    int px = (pg*64 + lane)*4;
    float4 r0 = *(const float4*)(tb + 0*L2 + px);
    float4 r1 = *(const float4*)(tb + 1*L2 + px);
    float4 r2 = *(const float4*)(tb + 2*L2 + px);
    float4 r3 = *(const float4*)(tb + 3*L2 + px);
    float4 o;
    o.x = fsoftplus(fmaf(w0,r0.x,fmaf(w1,r1.x,fmaf(w2,r2.x,fmaf(w3,r3.x,bb)))));
    o.y = fsoftplus(fmaf(w0,r0.y,fmaf(w1,r1.y,fmaf(w2,r2.y,fmaf(w3,r3.y,bb)))));
    o.z = fsoftplus(fmaf(w0,r0.z,fmaf(w1,r1.z,fmaf(w2,r2.z,fmaf(w3,r3.z,bb)))));
    o.w = fsoftplus(fmaf(w0,r0.w,fmaf(w1,r1.w,fmaf(w2,r2.w,fmaf(w3,r3.w,bb)))));
    *(float4*)(ob+px) = o;
  }
}

// ---------------- L: selective scan. block = (s,k,dgroup of 16); thread = (d_local, n)
__global__ __launch_bounds__(256) void k_scan(const float* __restrict__ dts,
    const float* __restrict__ xconv, const float* __restrict__ t36,
    const float* __restrict__ A_logs, const float* __restrict__ Ds, float* __restrict__ ys){
  const int P = 68;
  int bx = blockIdx.x; int dg = bx & 7; int k = (bx>>3)&3; int s = bx>>5;
  int tid = threadIdx.x; int n = tid & 15; int dl = tid >> 4;
  int d = dg*16 + dl;
  __shared__ float dt_s[2][16*P], u_s[2][16*P], B_s[2][16*P], C_s[2][16*P];
  __shared__ float y_s[16*P];
  float expA = fexp(A_logs[(k*DIC+d)*NST + n]);
  float aco = -expA * LOG2E;           // a = exp2(dt*aco) = exp(-dt*expA)
  float Dv = Ds[k*DIC+d];
  int r_st = tid >> 4;                  // staging row 0..15
  int i_st = (tid & 15) << 2;           // staging col (multiple of 4)
  const float* dtrow = dts   + ((size_t)(s*4+k)*DIC + dg*16 + r_st)*L2;
  const float* urow  = xconv + ((size_t)s*DIC + dg*16 + r_st)*L2;
  const float* Brow  = t36   + ((size_t)(s*4+k)*36 + 4 + r_st)*L2;
  const float* Crow  = t36   + ((size_t)(s*4+k)*36 + 20 + r_st)*L2;
  float* ysblk = ys + ((size_t)(s*4+k)*DIC + dg*16)*L2;

  auto load4 = [&](const float* rowp, int i0)->float4 {
    int ib = i0 + i_st;
    if (k==0){ return *(const float4*)(rowp + ib); }
    else if (k==2){
      float4 t = *(const float4*)(rowp + (1020 - ib));
      return make_float4(t.w, t.z, t.y, t.x);
    } else if (k==1){
      int p0 = ((ib&31)<<5) | (ib>>5);
      return make_float4(rowp[p0], rowp[p0+32], rowp[p0+64], rowp[p0+96]);
    } else {
      int idx = 1023 - ib;
      int p0 = ((idx&31)<<5) | (idx>>5);
      return make_float4(rowp[p0], rowp[p0-32], rowp[p0-64], rowp[p0-96]);
    }
  };

  float4 pdt = load4(dtrow, 0), pu = load4(urow, 0), pB = load4(Brow, 0), pC = load4(Crow, 0);
  int wofs = r_st*P + i_st;
  *(float4*)&dt_s[0][wofs] = pdt; *(float4*)&u_s[0][wofs] = pu;
  *(float4*)&B_s[0][wofs]  = pB;  *(float4*)&C_s[0][wofs] = pC;
  __syncthreads();

  float h = 0.f;
  int buf = 0;
  for (int c=0;c<16;++c){
    if (c < 15){
      int i0 = (c+1)*64;
      pdt = load4(dtrow, i0); pu = load4(urow, i0); pB = load4(Brow, i0); pC = load4(Crow, i0);
    }
    const float* dtp = &dt_s[buf][dl*P];
    const float* up  = &u_s[buf][dl*P];
    const float* Bp  = &B_s[buf][n*P];
    const float* Cp  = &C_s[buf][n*P];
    #pragma unroll 4
    for (int ii=0; ii<64; ii+=4){
      float4 dt4 = *(const float4*)(dtp+ii);
      float4 u4  = *(const float4*)(up+ii);
      float4 B4  = *(const float4*)(Bp+ii);
      float4 C4  = *(const float4*)(Cp+ii);
      #define SCAN_STEP(DT,U,BV,CV,IDX) { \
        float a_ = __builtin_amdgcn_exp2f((DT)*aco); \
        h = fmaf(a_, h, (DT)*(U)*(BV)); \
        float v_ = h*(CV); \
        v_ += __shfl_xor(v_,1,64); v_ += __shfl_xor(v_,2,64); \
        v_ += __shfl_xor(v_,4,64); v_ += __shfl_xor(v_,8,64); \
        if (n==0) y_s[dl*P + (IDX)] = fmaf((U), Dv, v_); }
      SCAN_STEP(dt4.x,u4.x,B4.x,C4.x, ii+0)
      SCAN_STEP(dt4.y,u4.y,B4.y,C4.y, ii+1)
      SCAN_STEP(dt4.z,u4.z,B4.z,C4.z, ii+2)
      SCAN_STEP(dt4.w,u4.w,B4.w,C4.w, ii+3)
      #undef SCAN_STEP
    }
    __syncthreads();
    float4 yv = *(float4*)&y_s[r_st*P + i_st];
    *(float4*)(ysblk + (size_t)r_st*L2 + c*64 + i_st) = yv;
    if (c < 15){
      int wb = buf^1;
      *(float4*)&dt_s[wb][wofs] = pdt; *(float4*)&u_s[wb][wofs] = pu;
      *(float4*)&B_s[wb][wofs]  = pB;  *(float4*)&C_s[wb][wofs] = pC;
    }
    __syncthreads();
    buf ^= 1;
  }
}

// ---------------- M1: combine 4 directions + out_norm LN(128) + *silu(z) -> yf (c-major)
__global__ __launch_bounds__(256) void k_combine(const float* __restrict__ ys,
    const float* __restrict__ z_t, const float* __restrict__ g, const float* __restrict__ b,
    float* __restrict__ yf){
  int wv = __builtin_amdgcn_readfirstlane(threadIdx.x>>6); int lane = threadIdx.x&63;
  int gp = blockIdx.x*4 + wv; int s = gp>>10; int p = gp&1023;
  int tp = ((p&31)<<5) | (p>>5);
  const float* yb = ys + (size_t)s*4*DIC*L2;
  int d0 = lane, d1 = lane+64;
  float ya = yb[(size_t)(0*DIC+d0)*L2 + p] + yb[(size_t)(2*DIC+d0)*L2 + (1023-p)]
           + yb[(size_t)(1*DIC+d0)*L2 + tp] + yb[(size_t)(3*DIC+d0)*L2 + (1023-tp)];
  float yc = yb[(size_t)(0*DIC+d1)*L2 + p] + yb[(size_t)(2*DIC+d1)*L2 + (1023-p)]
           + yb[(size_t)(1*DIC+d1)*L2 + tp] + yb[(size_t)(3*DIC+d1)*L2 + (1023-tp)];
  float sm = ya+yc, sq = ya*ya+yc*yc;
  for (int m=1;m<64;m<<=1){ sm+=__shfl_xor(sm,m,64); sq+=__shfl_xor(sq,m,64); }
  float mean = sm*(1.f/128.f); float var = sq*(1.f/128.f)-mean*mean;
  float rs = rsqrtf(var + 1e-5f);
  float yn0 = (ya-mean)*rs*g[d0] + b[d0];
  float yn1 = (yc-mean)*rs*g[d1] + b[d1];
  float zv0 = z_t[((size_t)s*DIC+d0)*L2 + p];
  float zv1 = z_t[((size_t)s*DIC+d1)*L2 + p];
  yf[((size_t)s*DIC+d0)*L2 + p] = yn0 * fsilu(zv0);
  yf[((size_t)s*DIC+d1)*L2 + p] = yn1 * fsilu(zv1);
}

// ---------------- M2a: xv = x + yf @ out_proj^T (c-major)
__global__ __launch_bounds__(256) void k_outproj(const float* __restrict__ yf,
    const float* __restrict__ x_cmaj, const float* __restrict__ W, float* __restrict__ xv){
  int bx = blockIdx.x; int cb = bx&3; int pg=(bx>>2)&15; int s=bx>>6;
  int lane = threadIdx.x&63;
  int cq = __builtin_amdgcn_readfirstlane(threadIdx.x>>6);
  int px = pg*64 + lane; int c0 = cb*16 + cq*4;
  const float* yb = yf + (size_t)s*DIC*L2 + px;
  float a0=0.f,a1=0.f,a2=0.f,a3=0.f;
  for (int dch=0;dch<DIC;++dch){
    float v = yb[(size_t)dch*L2];
    a0 = fmaf(W[(c0+0)*DIC+dch], v, a0);
    a1 = fmaf(W[(c0+1)*DIC+dch], v, a1);
    a2 = fmaf(W[(c0+2)*DIC+dch], v, a2);
    a3 = fmaf(W[(c0+3)*DIC+dch], v, a3);
  }
  size_t base = ((size_t)s*CCH+c0)*L2 + px;
  xv[base]        = x_cmaj[base]        + a0;
  xv[base+L2]     = x_cmaj[base+L2]     + a1;
  xv[base+2*L2]   = x_cmaj[base+2*L2]   + a2;
  xv[base+3*L2]   = x_cmaj[base+3*L2]   + a3;
}

// ---------------- M2b: ln2 + fc1 + gelu + fc2 + residual -> output (c-major)
__global__ __launch_bounds__(256) void k_mlp(const float* __restrict__ xv_in,
    const float* __restrict__ g, const float* __restrict__ b,
    const float* __restrict__ w1, const float* __restrict__ b1,
    const float* __restrict__ w2, const float* __restrict__ b2, float* __restrict__ out){
  int gp = blockIdx.x*256 + threadIdx.x; int s = gp>>10; int p = gp&1023;
  const float* xb = xv_in + (size_t)s*CCH*L2 + p;
  float xv[64];
  float sm=0.f;
  #pragma unroll
  for (int c=0;c<64;++c){ xv[c] = xb[(size_t)c*L2]; sm += xv[c]; }
  float mean = sm*(1.f/64.f);
  float sq=0.f;
  #pragma unroll
  for (int c=0;c<64;++c){ float dd = xv[c]-mean; sq += dd*dd; }
  float rs = rsqrtf(sq*(1.f/64.f) + 1e-5f);
  float xn[64];
  #pragma unroll
  for (int c=0;c<64;++c) xn[c] = (xv[c]-mean)*rs*g[c] + b[c];
  #pragma unroll
  for (int c=0;c<64;++c) xv[c] += b2[c];
  for (int o=0;o<64;++o){
    float acc = b1[o];
    #pragma unroll
    for (int c=0;c<64;++c) acc = fmaf(xn[c], w1[o*64+c], acc);
    float t = fgelu(acc);
    #pragma unroll
    for (int c=0;c<64;++c) xv[c] = fmaf(t, w2[c*64+o], xv[c]);
  }
  float* ob = out + (size_t)s*CCH*L2 + p;
  #pragma unroll
  for (int c=0;c<64;++c) ob[(size_t)c*L2] = xv[c];
}

extern "C" void kernel_launch(void* const* d_in, const int* in_sizes, int n_in,
                              void* d_out, int out_size, void* d_ws, size_t ws_size,
                              hipStream_t stream){
  (void)in_sizes; (void)n_in; (void)out_size; (void)ws_size;
  const float* img      = (const float*)d_in[0];
  const float* dz       = (const float*)d_in[1];
  const float* sg       = (const float*)d_in[2];
  const float* norm_g   = (const float*)d_in[3];
  const float* norm_b   = (const float*)d_in[4];
  const float* gn1_g    = (const float*)d_in[5];
  const float* gn1_b    = (const float*)d_in[6];
  const float* conv1_w  = (const float*)d_in[7];
  const float* conv1_b  = (const float*)d_in[8];
  const float* gn2_g    = (const float*)d_in[9];
  const float* gn2_b    = (const float*)d_in[10];
  const float* conv2_w  = (const float*)d_in[11];
  const float* conv2_b  = (const float*)d_in[12];
  const float* skip_w   = (const float*)d_in[13];
  const float* skip_b   = (const float*)d_in[14];
  const float* ln1_g    = (const float*)d_in[15];
  const float* ln1_b    = (const float*)d_in[16];
  const float* ln2_g    = (const float*)d_in[17];
  const float* ln2_b    = (const float*)d_in[18];
  const float* in_proj_w= (const float*)d_in[19];
  const float* dwconv_w = (const float*)d_in[20];
  const float* dwconv_b = (const float*)d_in[21];
  const float* x_proj_w = (const float*)d_in[22];
  const float* dt_proj_w= (const float*)d_in[23];
  const float* dt_proj_b= (const float*)d_in[24];
  const float* A_logs   = (const float*)d_in[25];
  const float* Ds       = (const float*)d_in[26];
  const float* out_norm_g = (const float*)d_in[27];
  const float* out_norm_b = (const float*)d_in[28];
  const float* out_proj_w = (const float*)d_in[29];
  const float* fc1_w    = (const float*)d_in[30];
  const float* fc1_b    = (const float*)d_in[31];
  const float* fc2_w    = (const float*)d_in[32];
  const float* fc2_b    = (const float*)d_in[33];

  float* ws = (float*)d_ws;
  float* x3c    = ws;                       // 1179648
  float* xact1  = x3c    + 1179648;         // 1179648
  float* h1     = xact1  + 1179648;         // 393216
  float* xact2  = h1     + 393216;          // 393216
  float* xp     = xact2  + 393216;          // 393216
  float* x_cmaj = xp     + 393216;          // 393216
  float* z_t    = x_cmaj + 393216;          // 786432
  float* xc     = z_t    + 786432;          // 786432
  float* xconv  = xc     + 786432;          // 786432
  float* t36    = xconv  + 786432;          // 884736
  float* dts    = t36    + 884736;          // 3145728
  float* ys     = dts    + 3145728;         // 3145728
  float* yf     = ys     + 3145728;         // 786432
  float* xv     = yf     + 786432;          // 393216
  float* stats  = xv     + 393216;          // 24

  k_ln2d_concat<<<24, 256, 0, stream>>>(img, dz, sg, norm_g, norm_b, x3c);
  k_gnstats<<<6, 256, 0, stream>>>(x3c, C3*L2, stats, 1e-5f);
  k_gnact<<<6*C3, 256, 0, stream>>>(x3c, stats, gn1_g, gn1_b, C3, xact1);
  k_conv3x3<C3><<<192, 256, 0, stream>>>(xact1, conv1_w, conv1_b, h1);
  k_gnstats<<<6, 256, 0, stream>>>(h1, CCH*L2, stats+12, 1e-5f);
  k_gnact<<<6*CCH, 256, 0, stream>>>(h1, stats+12, gn2_g, gn2_b, CCH, xact2);
  k_conv2_skip<<<192, 256, 0, stream>>>(xact2, x3c, conv2_w, conv2_b, skip_w, skip_b, xp, x_cmaj);
  k_ln1_inproj<<<96, 256, 0, stream>>>(xp, ln1_g, ln1_b, in_proj_w, xc, z_t);
  k_dwconv<<<768, 256, 0, stream>>>(xc, dwconv_w, dwconv_b, xconv);
  k_xproj<<<576, 256, 0, stream>>>(xconv, x_proj_w, t36);
  k_dt<<<768, dim3(64,4), 0, stream>>>(t36, dt_proj_w, dt_proj_b, dts);
  k_scan<<<192, 256, 0, stream>>>(dts, xconv, t36, A_logs, Ds, ys);
  k_combine<<<1536, 256, 0, stream>>>(ys, z_t, out_norm_g, out_norm_b, yf);
  k_outproj<<<384, 256, 0, stream>>>(yf, x_cmaj, out_proj_w, xv);
  k_mlp<<<24, 256, 0, stream>>>(xv, ln2_g, ln2_b, fc1_w, fc1_b, fc2_w, fc2_b, (float*)d_out);
}

// Round 2
// 624.403 us; speedup vs baseline: 1.2845x; 1.2845x over previous
//
#include <hip/hip_runtime.h>
#include <math.h>

// Problem dims
#define BL    6
#define CCH   64
#define C3    192
#define L2    1024
#define DIC   128
#define NST   16
#define K4    4

#define LOG2E 1.44269504088896340736f
#define LN2C  0.69314718055994530942f

__device__ __forceinline__ float fexp(float x){ return __builtin_amdgcn_exp2f(x*LOG2E); }
__device__ __forceinline__ float fsilu(float x){ return x / (1.f + fexp(-x)); }
__device__ __forceinline__ float fsoftplus(float x){
  if (x > 20.f) return x;
  return __builtin_amdgcn_logf(1.f + fexp(x)) * LN2C;
}
__device__ __forceinline__ float fgelu(float x){
  return 0.5f*x*(1.f + erff(x*0.70710678118654752440f));
}

// ---------------- A: per-pixel channel LayerNorm of frames + concat [dz, frames_n, sigma]
__global__ __launch_bounds__(256) void k_ln2d_concat(const float* __restrict__ img,
    const float* __restrict__ dz, const float* __restrict__ sg,
    const float* __restrict__ g, const float* __restrict__ b, float* __restrict__ x3c){
  int bx = blockIdx.x; int s = bx>>2; int p = ((bx&3)<<8) + threadIdx.x;
  int bsmp = s/3;
  const float* fr = img + s*CCH*L2;
  float sm=0.f, sq=0.f;
  for (int c=0;c<CCH;++c){ float v = fr[c*L2+p]; sm+=v; sq+=v*v; }
  float mean = sm*(1.f/CCH); float var = sq*(1.f/CCH) - mean*mean;
  float rs = rsqrtf(var + 1e-6f);
  float* o = x3c + s*C3*L2;
  const float* dzp = dz + bsmp*CCH*L2;
  const float* sgp = sg + bsmp*CCH*L2;
  for (int c=0;c<CCH;++c){
    o[c*L2+p] = dzp[c*L2+p];
    float v = fr[c*L2+p];
    o[(CCH+c)*L2+p] = (v-mean)*rs*g[c] + b[c];
    o[(2*CCH+c)*L2+p] = sgp[c*L2+p];
  }
}

// ---------------- B/E: GroupNorm(1) stats per sample
__global__ __launch_bounds__(256) void k_gnstats(const float* __restrict__ x, int elems_per_s,
    float* __restrict__ stats, float eps){
  int s = blockIdx.x; int tid = threadIdx.x;
  const float* xs = x + (size_t)s*elems_per_s;
  float sm=0.f, sq=0.f;
  for (int idx = tid*4; idx < elems_per_s; idx += 256*4){
    float4 v = *(const float4*)(xs+idx);
    sm += v.x+v.y+v.z+v.w;
    sq += v.x*v.x+v.y*v.y+v.z*v.z+v.w*v.w;
  }
  for (int m=1;m<64;m<<=1){ sm+=__shfl_xor(sm,m,64); sq+=__shfl_xor(sq,m,64); }
  __shared__ float s_sm[4], s_sq[4];
  int wv = tid>>6;
  if ((tid&63)==0){ s_sm[wv]=sm; s_sq[wv]=sq; }
  __syncthreads();
  if (tid==0){
    float S = s_sm[0]+s_sm[1]+s_sm[2]+s_sm[3];
    float Q = s_sq[0]+s_sq[1]+s_sq[2]+s_sq[3];
    float mean = S/elems_per_s; float var = Q/elems_per_s - mean*mean;
    stats[s*2] = mean; stats[s*2+1] = rsqrtf(var+eps);
  }
}

// ---------------- C/F: apply GN affine + SiLU elementwise (ch = channels per sample)
__global__ __launch_bounds__(256) void k_gnact(const float* __restrict__ x,
    const float* __restrict__ stats, const float* __restrict__ g, const float* __restrict__ b,
    int ch, float* __restrict__ out){
  int bx = blockIdx.x;
  int s = bx / ch; int c = bx % ch;
  float mean = stats[s*2], rs = stats[s*2+1];
  float gc = g[c]*rs; float bc = b[c] - mean*rs*g[c];
  size_t base = (size_t)bx*1024 + threadIdx.x*4;
  float4 v = *(const float4*)(x + base);
  float t0 = v.x*gc+bc, t1 = v.y*gc+bc, t2 = v.z*gc+bc, t3 = v.w*gc+bc;
  float4 o; o.x = fsilu(t0); o.y = fsilu(t1); o.z = fsilu(t2); o.w = fsilu(t3);
  *(float4*)(out + base) = o;
}

// conv row helper: accumulate 3 taps for 2 output channels over a 4-px quad
__device__ __forceinline__ void conv_row_acc(float4& a0, float4& a1, float4 mid, float lf, float rt,
    const float* wp0, const float* wp1){
  float w0=wp0[0], w1=wp0[1], w2=wp0[2];
  a0.x = fmaf(w0,lf,   fmaf(w1,mid.x, fmaf(w2,mid.y, a0.x)));
  a0.y = fmaf(w0,mid.x,fmaf(w1,mid.y, fmaf(w2,mid.z, a0.y)));
  a0.z = fmaf(w0,mid.y,fmaf(w1,mid.z, fmaf(w2,mid.w, a0.z)));
  a0.w = fmaf(w0,mid.z,fmaf(w1,mid.w, fmaf(w2,rt,    a0.w)));
  float v0=wp1[0], v1=wp1[1], v2=wp1[2];
  a1.x = fmaf(v0,lf,   fmaf(v1,mid.x, fmaf(v2,mid.y, a1.x)));
  a1.y = fmaf(v0,mid.x,fmaf(v1,mid.y, fmaf(v2,mid.z, a1.y)));
  a1.z = fmaf(v0,mid.y,fmaf(v1,mid.z, fmaf(v2,mid.w, a1.z)));
  a1.w = fmaf(v0,mid.z,fmaf(v1,mid.w, fmaf(v2,rt,    a1.w)));
}

// ---------------- D: 3x3 conv, CI input ch -> 64 out ch, 2 out ch per block
template<int CI>
__global__ __launch_bounds__(256) void k_conv3x3(const float* __restrict__ xin_,
    const float* __restrict__ w, const float* __restrict__ bias, float* __restrict__ out){
  int bx = blockIdx.x; int cop = bx & 31; int s = bx >> 5;
  int co0 = cop*2, co1 = co0+1;
  int tid = threadIdx.x; int row = tid>>3; int q = tid&7; int col0 = q*4;
  int p = row*32+col0;
  float b0 = bias[co0], b1v = bias[co1];
  float4 a0 = make_float4(b0,b0,b0,b0);
  float4 a1 = make_float4(b1v,b1v,b1v,b1v);
  const float* xin = xin_ + (size_t)s*CI*L2;
  for (int ci=0; ci<CI; ++ci){
    const float* xr = xin + ci*L2;
    const float* wb0 = w + (size_t)(co0*CI + ci)*9;
    const float* wb1 = w + (size_t)(co1*CI + ci)*9;
    #pragma unroll
    for (int dy=-1; dy<=1; ++dy){
      int r = row+dy;
      float4 mid = make_float4(0.f,0.f,0.f,0.f);
      if (0 <= r && r < 32) mid = *(const float4*)(xr + r*32 + col0);
      float lf = __shfl_up(mid.w, 1, 64); if (q==0) lf = 0.f;
      float rt = __shfl_down(mid.x, 1, 64); if (q==7) rt = 0.f;
      conv_row_acc(a0, a1, mid, lf, rt, wb0 + (dy+1)*3, wb1 + (dy+1)*3);
    }
  }
  *(float4*)(out + ((size_t)s*CCH+co0)*L2 + p) = a0;
  *(float4*)(out + ((size_t)s*CCH+co1)*L2 + p) = a1;
}

// ---------------- G: conv2(3x3) + skip(1x1 over x3c) -> x in both layouts
__global__ __launch_bounds__(256) void k_conv2_skip(const float* __restrict__ xact2,
    const float* __restrict__ x3c, const float* __restrict__ w2, const float* __restrict__ b2,
    const float* __restrict__ wsk, const float* __restrict__ bsk,
    float* __restrict__ xp, float* __restrict__ x_cmaj){
  int bx = blockIdx.x; int cop = bx & 31; int s = bx >> 5;
  int co0 = cop*2, co1 = co0+1;
  int tid = threadIdx.x; int row = tid>>3; int q = tid&7; int col0 = q*4;
  int p = row*32+col0;
  float bi0 = b2[co0]+bsk[co0], bi1 = b2[co1]+bsk[co1];
  float4 a0 = make_float4(bi0,bi0,bi0,bi0);
  float4 a1 = make_float4(bi1,bi1,bi1,bi1);
  const float* xin = xact2 + (size_t)s*CCH*L2;
  for (int ci=0; ci<CCH; ++ci){
    const float* xr = xin + ci*L2;
    const float* wb0 = w2 + (size_t)(co0*CCH + ci)*9;
    const float* wb1 = w2 + (size_t)(co1*CCH + ci)*9;
    #pragma unroll
    for (int dy=-1; dy<=1; ++dy){
      int r = row+dy;
      float4 mid = make_float4(0.f,0.f,0.f,0.f);
      if (0 <= r && r < 32) mid = *(const float4*)(xr + r*32 + col0);
      float lf = __shfl_up(mid.w, 1, 64); if (q==0) lf = 0.f;
      float rt = __shfl_down(mid.x, 1, 64); if (q==7) rt = 0.f;
      conv_row_acc(a0, a1, mid, lf, rt, wb0 + (dy+1)*3, wb1 + (dy+1)*3);
    }
  }
  const float* x3 = x3c + (size_t)s*C3*L2 + p;
  for (int ci=0; ci<C3; ++ci){
    float4 v = *(const float4*)(x3 + ci*L2);
    float ws0 = wsk[co0*C3+ci], ws1 = wsk[co1*C3+ci];
    a0.x = fmaf(ws0,v.x,a0.x); a0.y = fmaf(ws0,v.y,a0.y); a0.z = fmaf(ws0,v.z,a0.z); a0.w = fmaf(ws0,v.w,a0.w);
    a1.x = fmaf(ws1,v.x,a1.x); a1.y = fmaf(ws1,v.y,a1.y); a1.z = fmaf(ws1,v.z,a1.z); a1.w = fmaf(ws1,v.w,a1.w);
  }
  *(float4*)(x_cmaj + ((size_t)s*CCH+co0)*L2 + p) = a0;
  *(float4*)(x_cmaj + ((size_t)s*CCH+co1)*L2 + p) = a1;
  float* xpb = xp + ((size_t)s*L2 + p)*CCH;
  xpb[co0] = a0.x; xpb[CCH+co0] = a0.y; xpb[2*CCH+co0] = a0.z; xpb[3*CCH+co0] = a0.w;
  xpb[co1] = a1.x; xpb[CCH+co1] = a1.y; xpb[2*CCH+co1] = a1.z; xpb[3*CCH+co1] = a1.w;
}

// ---------------- H: ln1 + in_proj (256 outputs); split into xc (c-major) and z (c-major)
__global__ __launch_bounds__(256) void k_ln1_inproj(const float* __restrict__ xp,
    const float* __restrict__ g, const float* __restrict__ b, const float* __restrict__ W,
    float* __restrict__ xc, float* __restrict__ z_t){
  __shared__ float xn_s[64*65];
  int s = blockIdx.x >> 4; int p0 = (blockIdx.x & 15)*64;
  int tid = threadIdx.x; int wv = __builtin_amdgcn_readfirstlane(tid>>6); int lane = tid&63;
  for (int j=0;j<16;++j){
    int pl = wv*16 + j; int p = p0 + pl;
    float v = xp[((size_t)s*L2 + p)*CCH + lane];
    float sm = v, sq = v*v;
    for (int m=1;m<64;m<<=1){ sm += __shfl_xor(sm,m,64); sq += __shfl_xor(sq,m,64); }
    float mean = sm*(1.f/64.f); float var = sq*(1.f/64.f) - mean*mean;
    float rs = rsqrtf(var + 1e-5f);
    xn_s[pl*65 + lane] = (v-mean)*rs*g[lane] + b[lane];
  }
  __syncthreads();
  int px_l = tid & 63;
  int og = __builtin_amdgcn_readfirstlane(tid >> 6);
  int o0 = og*64;
  float acc[64];
  #pragma unroll
  for (int oi=0;oi<64;++oi) acc[oi]=0.f;
  for (int c=0;c<64;++c){
    float xv = xn_s[px_l*65 + c];
    #pragma unroll
    for (int oi=0;oi<64;++oi) acc[oi] = fmaf(W[(o0+oi)*64 + c], xv, acc[oi]);
  }
  int p = p0 + px_l;
  if (og < 2){
    #pragma unroll
    for (int oi=0;oi<64;++oi) xc[((size_t)s*DIC + o0 + oi)*L2 + p] = acc[oi];
  } else {
    #pragma unroll
    for (int oi=0;oi<64;++oi) z_t[((size_t)s*DIC + (o0-128) + oi)*L2 + p] = acc[oi];
  }
}

// ---------------- I: depthwise 3x3 conv + bias + SiLU
__global__ __launch_bounds__(256) void k_dwconv(const float* __restrict__ xc,
    const float* __restrict__ w, const float* __restrict__ bias, float* __restrict__ xconv){
  int bx = blockIdx.x; int dch = bx & 127; int s = bx >> 7;
  int tid = threadIdx.x; int row = tid>>3; int q = tid&7; int col0 = q*4;
  const float* xr = xc + ((size_t)s*DIC+dch)*L2;
  const float* wp = w + dch*9;
  float bv = bias[dch];
  float4 acc = make_float4(bv,bv,bv,bv);
  #pragma unroll
  for (int dy=-1;dy<=1;++dy){
    int r = row+dy;
    float4 mid = make_float4(0.f,0.f,0.f,0.f);
    if (0<=r && r<32) mid = *(const float4*)(xr + r*32 + col0);
    float lf = __shfl_up(mid.w,1,64); if(q==0) lf=0.f;
    float rt = __shfl_down(mid.x,1,64); if(q==7) rt=0.f;
    float w0=wp[(dy+1)*3], w1=wp[(dy+1)*3+1], w2=wp[(dy+1)*3+2];
    acc.x = fmaf(w0,lf,   fmaf(w1,mid.x, fmaf(w2,mid.y, acc.x)));
    acc.y = fmaf(w0,mid.x,fmaf(w1,mid.y, fmaf(w2,mid.z, acc.y)));
    acc.z = fmaf(w0,mid.y,fmaf(w1,mid.z, fmaf(w2,mid.w, acc.z)));
    acc.w = fmaf(w0,mid.z,fmaf(w1,mid.w, fmaf(w2,rt,    acc.w)));
  }
  acc.x = fsilu(acc.x); acc.y = fsilu(acc.y); acc.z = fsilu(acc.z); acc.w = fsilu(acc.w);
  *(float4*)(xconv + ((size_t)s*DIC+dch)*L2 + row*32+col0) = acc;
}

// ---------------- J: x_proj: t36[s,k,c,p] = sum_d Xw[k,c,d]*xconv[s,d,p] (pixel order)
__global__ __launch_bounds__(256) void k_xproj(const float* __restrict__ xconv,
    const float* __restrict__ W, float* __restrict__ t36){
  int bx = blockIdx.x;
  int pg = bx & 3; int t = bx >> 2;
  int cg = t % 6; int t2 = t / 6;
  int k = t2 & 3; int s = t2 >> 2;
  int px = pg*256 + threadIdx.x;
  const float* xb = xconv + (size_t)s*DIC*L2 + px;
  const float* wb = W + (size_t)(k*36 + cg*6)*DIC;
  float acc[6] = {0.f,0.f,0.f,0.f,0.f,0.f};
  for (int dch=0; dch<DIC; ++dch){
    float v = xb[(size_t)dch*L2];
    #pragma unroll
    for (int ci=0; ci<6; ++ci) acc[ci] = fmaf(wb[ci*DIC+dch], v, acc[ci]);
  }
  float* ob = t36 + ((size_t)(s*4+k)*36 + cg*6)*L2 + px;
  #pragma unroll
  for (int ci=0;ci<6;++ci) ob[(size_t)ci*L2] = acc[ci];
}

// ---------------- K: dt = softplus(dt_proj(t36[0:4]) + bias), pixel order
__global__ void k_dt(const float* __restrict__ t36, const float* __restrict__ dtw,
    const float* __restrict__ dtb, float* __restrict__ dts){
  int dgrp = blockIdx.x & 31; int k = (blockIdx.x>>5)&3; int s = blockIdx.x>>7;
  int lane = threadIdx.x;
  int dl = __builtin_amdgcn_readfirstlane(threadIdx.y);
  int dch = dgrp*4 + dl;
  const float* tb = t36 + (size_t)(s*4+k)*36*L2;
  float w0 = dtw[(k*DIC+dch)*4+0], w1 = dtw[(k*DIC+dch)*4+1];
  float w2 = dtw[(k*DIC+dch)*4+2], w3 = dtw[(k*DIC+dch)*4+3];
  float bb = dtb[k*DIC+dch];
  float* ob = dts + ((size_t)(s*4+k)*DIC + dch)*L2;
  for (int pg=0; pg<4; ++pg){
    int px = (pg*64 + lane)*4;
    float4 r0 = *(const float4*)(tb + 0*L2 + px);
    float4 r1 = *(const float4*)(tb + 1*L2 + px);
    float4 r2 = *(const float4*)(tb + 2*L2 + px);
    float4 r3 = *(const float4*)(tb + 3*L2 + px);
    float4 o;
    o.x = fsoftplus(fmaf(w0,r0.x,fmaf(w1,r1.x,fmaf(w2,r2.x,fmaf(w3,r3.x,bb)))));
    o.y = fsoftplus(fmaf(w0,r0.y,fmaf(w1,r1.y,fmaf(w2,r2.y,fmaf(w3,r3.y,bb)))));
    o.z = fsoftplus(fmaf(w0,r0.z,fmaf(w1,r1.z,fmaf(w2,r2.z,fmaf(w3,r3.z,bb)))));
    o.w = fsoftplus(fmaf(w0,r0.w,fmaf(w1,r1.w,fmaf(w2,r2.w,fmaf(w3,r3.w,bb)))));
    *(float4*)(ob+px) = o;
  }
}

// ======== Selective scan: 2-pass chunked parallel scan (16 chunks of 64 steps) ========
// Direction-aware gather of 4 consecutive scan positions for (k in 0..3)
__device__ __forceinline__ float4 scan_load4(const float* __restrict__ rowp, int ib, int k){
  if (k==0){ return *(const float4*)(rowp + ib); }
  else if (k==2){
    float4 t = *(const float4*)(rowp + (1020 - ib));
    return make_float4(t.w, t.z, t.y, t.x);
  } else if (k==1){
    int p0 = ((ib&31)<<5) | (ib>>5);
    return make_float4(rowp[p0], rowp[p0+32], rowp[p0+64], rowp[p0+96]);
  } else {
    int idx = 1023 - ib;
    int p0 = ((idx&31)<<5) | (idx>>5);
    return make_float4(rowp[p0], rowp[p0-32], rowp[p0-64], rowp[p0-96]);
  }
}

// Phase A: per (s,k,dg,chunk): local scan from h=0 over 64 steps -> h_end, prod(a)
__global__ __launch_bounds__(256) void k_scan_part(const float* __restrict__ dts,
    const float* __restrict__ xconv, const float* __restrict__ t36,
    const float* __restrict__ A_logs, float* __restrict__ hend, float* __restrict__ prodA){
  const int P = 68;
  int bx = blockIdx.x; int ch = bx & 15; int dg = (bx>>4)&7; int k = (bx>>7)&3; int s = bx>>9;
  int tid = threadIdx.x; int n = tid & 15; int dl = tid >> 4;
  int d = dg*16 + dl;
  __shared__ float dt_s[16*P], u_s[16*P], B_s[16*P];
  float expA = fexp(A_logs[(k*DIC+d)*NST + n]);
  float aco = -expA * LOG2E;
  int r_st = tid >> 4; int i_st = (tid & 15) << 2;
  const float* dtrow = dts   + ((size_t)(s*4+k)*DIC + dg*16 + r_st)*L2;
  const float* urow  = xconv + ((size_t)s*DIC + dg*16 + r_st)*L2;
  const float* Brow  = t36   + ((size_t)(s*4+k)*36 + 4 + r_st)*L2;
  int ib = ch*64 + i_st;
  int wofs = r_st*P + i_st;
  *(float4*)&dt_s[wofs] = scan_load4(dtrow, ib, k);
  *(float4*)&u_s[wofs]  = scan_load4(urow,  ib, k);
  *(float4*)&B_s[wofs]  = scan_load4(Brow,  ib, k);
  __syncthreads();
  const float* dtp = &dt_s[dl*P];
  const float* up  = &u_s[dl*P];
  const float* Bp  = &B_s[n*P];
  float h = 0.f, Pr = 1.f;
  #pragma unroll 4
  for (int ii=0; ii<64; ii+=4){
    float4 dt4 = *(const float4*)(dtp+ii);
    float4 u4  = *(const float4*)(up+ii);
    float4 B4  = *(const float4*)(Bp+ii);
    #define PART_STEP(DT,U,BV) { \
      float a_ = __builtin_amdgcn_exp2f((DT)*aco); \
      h = fmaf(a_, h, (DT)*(U)*(BV)); \
      Pr *= a_; }
    PART_STEP(dt4.x,u4.x,B4.x)
    PART_STEP(dt4.y,u4.y,B4.y)
    PART_STEP(dt4.z,u4.z,B4.z)
    PART_STEP(dt4.w,u4.w,B4.w)
    #undef PART_STEP
  }
  size_t seq = (size_t)(s*4+k)*DIC + d;
  hend [(seq*16+n)*16 + ch] = h;
  prodA[(seq*16+n)*16 + ch] = Pr;
}

// Phase B: serial prefix over 16 chunks per (seq,n) -> initial state of each chunk
__global__ __launch_bounds__(256) void k_scan_fix(const float* __restrict__ hend,
    const float* __restrict__ prodA, float* __restrict__ Hin){
  int t = blockIdx.x*256 + threadIdx.x;   // 49152 = 3072 seq * 16 n
  const float* he = hend  + (size_t)t*16;
  const float* pa = prodA + (size_t)t*16;
  float* hi = Hin + (size_t)t*16;
  float H = 0.f;
  #pragma unroll
  for (int c=0;c<16;++c){ hi[c] = H; H = fmaf(pa[c], H, he[c]); }
}

// Phase C: per (s,k,dg,chunk): re-run local scan from correct Hin, emit y
__global__ __launch_bounds__(256) void k_scan_y(const float* __restrict__ dts,
    const float* __restrict__ xconv, const float* __restrict__ t36,
    const float* __restrict__ A_logs, const float* __restrict__ Ds,
    const float* __restrict__ Hin, float* __restrict__ ys){
  const int P = 68;
  int bx = blockIdx.x; int ch = bx & 15; int dg = (bx>>4)&7; int k = (bx>>7)&3; int s = bx>>9;
  int tid = threadIdx.x; int n = tid & 15; int dl = tid >> 4;
  int d = dg*16 + dl;
  __shared__ float dt_s[16*P], u_s[16*P], B_s[16*P], C_s[16*P];
  __shared__ float y_s[16*P];
  float expA = fexp(A_logs[(k*DIC+d)*NST + n]);
  float aco = -expA * LOG2E;
  float Dv = Ds[k*DIC+d];
  int r_st = tid >> 4; int i_st = (tid & 15) << 2;
  const float* dtrow = dts   + ((size_t)(s*4+k)*DIC + dg*16 + r_st)*L2;
  const float* urow  = xconv + ((size_t)s*DIC + dg*16 + r_st)*L2;
  const float* Brow  = t36   + ((size_t)(s*4+k)*36 + 4 + r_st)*L2;
  const float* Crow  = t36   + ((size_t)(s*4+k)*36 + 20 + r_st)*L2;
  int ib = ch*64 + i_st;
  int wofs = r_st*P + i_st;
  *(float4*)&dt_s[wofs] = scan_load4(dtrow, ib, k);
  *(float4*)&u_s[wofs]  = scan_load4(urow,  ib, k);
  *(float4*)&B_s[wofs]  = scan_load4(Brow,  ib, k);
  *(float4*)&C_s[wofs]  = scan_load4(Crow,  ib, k);
  size_t seq = (size_t)(s*4+k)*DIC + d;
  float h = Hin[(seq*16+n)*16 + ch];
  __syncthreads();
  const float* dtp = &dt_s[dl*P];
  const float* up  = &u_s[dl*P];
  const float* Bp  = &B_s[n*P];
  const float* Cp  = &C_s[n*P];
  #pragma unroll 4
  for (int ii=0; ii<64; ii+=4){
    float4 dt4 = *(const float4*)(dtp+ii);
    float4 u4  = *(const float4*)(up+ii);
    float4 B4  = *(const float4*)(Bp+ii);
    float4 C4  = *(const float4*)(Cp+ii);
    #define SCAN_STEP(DT,U,BV,CV,IDX) { \
      float a_ = __builtin_amdgcn_exp2f((DT)*aco); \
      h = fmaf(a_, h, (DT)*(U)*(BV)); \
      float v_ = h*(CV); \
      v_ += __shfl_xor(v_,1,64); v_ += __shfl_xor(v_,2,64); \
      v_ += __shfl_xor(v_,4,64); v_ += __shfl_xor(v_,8,64); \
      if (n==0) y_s[dl*P + (IDX)] = fmaf((U), Dv, v_); }
    SCAN_STEP(dt4.x,u4.x,B4.x,C4.x, ii+0)
    SCAN_STEP(dt4.y,u4.y,B4.y,C4.y, ii+1)
    SCAN_STEP(dt4.z,u4.z,B4.z,C4.z, ii+2)
    SCAN_STEP(dt4.w,u4.w,B4.w,C4.w, ii+3)
    #undef SCAN_STEP
  }
  __syncthreads();
  float4 yv = *(float4*)&y_s[r_st*P + i_st];
  float* ysblk = ys + ((size_t)(s*4+k)*DIC + dg*16)*L2;
  *(float4*)(ysblk + (size_t)r_st*L2 + ch*64 + i_st) = yv;
}

// ---------------- M1: combine 4 directions + out_norm LN(128) + *silu(z) -> yf (c-major)
__global__ __launch_bounds__(256) void k_combine(const float* __restrict__ ys,
    const float* __restrict__ z_t, const float* __restrict__ g, const float* __restrict__ b,
    float* __restrict__ yf){
  int wv = __builtin_amdgcn_readfirstlane(threadIdx.x>>6); int lane = threadIdx.x&63;
  int gp = blockIdx.x*4 + wv; int s = gp>>10; int p = gp&1023;
  int tp = ((p&31)<<5) | (p>>5);
  const float* yb = ys + (size_t)s*4*DIC*L2;
  int d0 = lane, d1 = lane+64;
  float ya = yb[(size_t)(0*DIC+d0)*L2 + p] + yb[(size_t)(2*DIC+d0)*L2 + (1023-p)]
           + yb[(size_t)(1*DIC+d0)*L2 + tp] + yb[(size_t)(3*DIC+d0)*L2 + (1023-tp)];
  float yc = yb[(size_t)(0*DIC+d1)*L2 + p] + yb[(size_t)(2*DIC+d1)*L2 + (1023-p)]
           + yb[(size_t)(1*DIC+d1)*L2 + tp] + yb[(size_t)(3*DIC+d1)*L2 + (1023-tp)];
  float sm = ya+yc, sq = ya*ya+yc*yc;
  for (int m=1;m<64;m<<=1){ sm+=__shfl_xor(sm,m,64); sq+=__shfl_xor(sq,m,64); }
  float mean = sm*(1.f/128.f); float var = sq*(1.f/128.f)-mean*mean;
  float rs = rsqrtf(var + 1e-5f);
  float yn0 = (ya-mean)*rs*g[d0] + b[d0];
  float yn1 = (yc-mean)*rs*g[d1] + b[d1];
  float zv0 = z_t[((size_t)s*DIC+d0)*L2 + p];
  float zv1 = z_t[((size_t)s*DIC+d1)*L2 + p];
  yf[((size_t)s*DIC+d0)*L2 + p] = yn0 * fsilu(zv0);
  yf[((size_t)s*DIC+d1)*L2 + p] = yn1 * fsilu(zv1);
}

// ---------------- M2a: xv = x + yf @ out_proj^T (c-major)
__global__ __launch_bounds__(256) void k_outproj(const float* __restrict__ yf,
    const float* __restrict__ x_cmaj, const float* __restrict__ W, float* __restrict__ xv){
  int bx = blockIdx.x; int cb = bx&3; int pg=(bx>>2)&15; int s=bx>>6;
  int lane = threadIdx.x&63;
  int cq = __builtin_amdgcn_readfirstlane(threadIdx.x>>6);
  int px = pg*64 + lane; int c0 = cb*16 + cq*4;
  const float* yb = yf + (size_t)s*DIC*L2 + px;
  float a0=0.f,a1=0.f,a2=0.f,a3=0.f;
  for (int dch=0;dch<DIC;++dch){
    float v = yb[(size_t)dch*L2];
    a0 = fmaf(W[(c0+0)*DIC+dch], v, a0);
    a1 = fmaf(W[(c0+1)*DIC+dch], v, a1);
    a2 = fmaf(W[(c0+2)*DIC+dch], v, a2);
    a3 = fmaf(W[(c0+3)*DIC+dch], v, a3);
  }
  size_t base = ((size_t)s*CCH+c0)*L2 + px;
  xv[base]        = x_cmaj[base]        + a0;
  xv[base+L2]     = x_cmaj[base+L2]     + a1;
  xv[base+2*L2]   = x_cmaj[base+2*L2]   + a2;
  xv[base+3*L2]   = x_cmaj[base+3*L2]   + a3;
}

// ---------------- M2b: ln2 + fc1 + gelu + fc2 + residual -> output (c-major)
// Tile version: block = 64 pixels; LDS staging; 16-elem register accumulators only.
__global__ __launch_bounds__(256) void k_mlp(const float* __restrict__ xv_in,
    const float* __restrict__ g, const float* __restrict__ b,
    const float* __restrict__ w1, const float* __restrict__ b1,
    const float* __restrict__ w2, const float* __restrict__ b2, float* __restrict__ out){
  __shared__ float xt[64*65];   // [c][px]
  __shared__ float ts[64*65];   // [px][o]
  int s = blockIdx.x >> 4; int p0 = (blockIdx.x & 15)*64;
  int tid = threadIdx.x; int lane = tid & 63;
  int grp = __builtin_amdgcn_readfirstlane(tid >> 6);
  // load 64x64 tile (coalesced per channel row)
  for (int j=0;j<16;++j){
    int c = grp*16 + j;
    xt[c*65 + lane] = xv_in[((size_t)s*CCH + c)*L2 + p0 + lane];
  }
  __syncthreads();
  // per-pixel LN stats (lane = pixel; redundant across groups)
  float sm=0.f, sq=0.f;
  for (int c=0;c<64;++c){ float v = xt[c*65+lane]; sm+=v; sq+=v*v; }
  float mean = sm*(1.f/64.f);
  float rs = rsqrtf(sq*(1.f/64.f) - mean*mean + 1e-5f);
  // fc1 + gelu for this group's 16 hidden units
  int o0 = grp*16;
  float t[16];
  #pragma unroll
  for (int oi=0;oi<16;++oi) t[oi] = b1[o0+oi];
  for (int c=0;c<64;++c){
    float xn = (xt[c*65+lane]-mean)*rs*g[c] + b[c];
    #pragma unroll
    for (int oi=0;oi<16;++oi) t[oi] = fmaf(xn, w1[(o0+oi)*64 + c], t[oi]);
  }
  #pragma unroll
  for (int oi=0;oi<16;++oi) ts[lane*65 + o0+oi] = fgelu(t[oi]);
  __syncthreads();
  // fc2 + residual for this group's 16 output channels
  int c0 = grp*16;
  float acc[16];
  #pragma unroll
  for (int ci=0;ci<16;++ci) acc[ci] = xt[(c0+ci)*65+lane] + b2[c0+ci];
  for (int o=0;o<64;++o){
    float tv = ts[lane*65 + o];
    #pragma unroll
    for (int ci=0;ci<16;++ci) acc[ci] = fmaf(tv, w2[(c0+ci)*64 + o], acc[ci]);
  }
  #pragma unroll
  for (int ci=0;ci<16;++ci) out[((size_t)s*CCH + c0+ci)*L2 + p0 + lane] = acc[ci];
}

extern "C" void kernel_launch(void* const* d_in, const int* in_sizes, int n_in,
                              void* d_out, int out_size, void* d_ws, size_t ws_size,
                              hipStream_t stream){
  (void)in_sizes; (void)n_in; (void)out_size; (void)ws_size;
  const float* img      = (const float*)d_in[0];
  const float* dz       = (const float*)d_in[1];
  const float* sg       = (const float*)d_in[2];
  const float* norm_g   = (const float*)d_in[3];
  const float* norm_b   = (const float*)d_in[4];
  const float* gn1_g    = (const float*)d_in[5];
  const float* gn1_b    = (const float*)d_in[6];
  const float* conv1_w  = (const float*)d_in[7];
  const float* conv1_b  = (const float*)d_in[8];
  const float* gn2_g    = (const float*)d_in[9];
  const float* gn2_b    = (const float*)d_in[10];
  const float* conv2_w  = (const float*)d_in[11];
  const float* conv2_b  = (const float*)d_in[12];
  const float* skip_w   = (const float*)d_in[13];
  const float* skip_b   = (const float*)d_in[14];
  const float* ln1_g    = (const float*)d_in[15];
  const float* ln1_b    = (const float*)d_in[16];
  const float* ln2_g    = (const float*)d_in[17];
  const float* ln2_b    = (const float*)d_in[18];
  const float* in_proj_w= (const float*)d_in[19];
  const float* dwconv_w = (const float*)d_in[20];
  const float* dwconv_b = (const float*)d_in[21];
  const float* x_proj_w = (const float*)d_in[22];
  const float* dt_proj_w= (const float*)d_in[23];
  const float* dt_proj_b= (const float*)d_in[24];
  const float* A_logs   = (const float*)d_in[25];
  const float* Ds       = (const float*)d_in[26];
  const float* out_norm_g = (const float*)d_in[27];
  const float* out_norm_b = (const float*)d_in[28];
  const float* out_proj_w = (const float*)d_in[29];
  const float* fc1_w    = (const float*)d_in[30];
  const float* fc1_b    = (const float*)d_in[31];
  const float* fc2_w    = (const float*)d_in[32];
  const float* fc2_b    = (const float*)d_in[33];

  float* ws = (float*)d_ws;
  float* x3c    = ws;                       // 1179648
  float* xact1  = x3c    + 1179648;         // 1179648
  float* h1     = xact1  + 1179648;         // 393216
  float* xact2  = h1     + 393216;          // 393216
  float* xp     = xact2  + 393216;          // 393216
  float* x_cmaj = xp     + 393216;          // 393216
  float* z_t    = x_cmaj + 393216;          // 786432
  float* xc     = z_t    + 786432;          // 786432
  float* xconv  = xc     + 786432;          // 786432
  float* t36    = xconv  + 786432;          // 884736
  float* dts    = t36    + 884736;          // 3145728
  float* ys     = dts    + 3145728;         // 3145728
  float* yf     = ys     + 3145728;         // 786432
  float* xv     = yf     + 786432;          // 393216
  float* stats  = xv     + 393216;          // 24
  // scan scratch reuses x3c+xact1 (dead after conv2_skip/conv1): 3*786432 = 2359296 floats
  float* hend   = x3c;
  float* prodA  = x3c + 786432;
  float* Hin    = x3c + 1572864;

  k_ln2d_concat<<<24, 256, 0, stream>>>(img, dz, sg, norm_g, norm_b, x3c);
  k_gnstats<<<6, 256, 0, stream>>>(x3c, C3*L2, stats, 1e-5f);
  k_gnact<<<6*C3, 256, 0, stream>>>(x3c, stats, gn1_g, gn1_b, C3, xact1);
  k_conv3x3<C3><<<192, 256, 0, stream>>>(xact1, conv1_w, conv1_b, h1);
  k_gnstats<<<6, 256, 0, stream>>>(h1, CCH*L2, stats+12, 1e-5f);
  k_gnact<<<6*CCH, 256, 0, stream>>>(h1, stats+12, gn2_g, gn2_b, CCH, xact2);
  k_conv2_skip<<<192, 256, 0, stream>>>(xact2, x3c, conv2_w, conv2_b, skip_w, skip_b, xp, x_cmaj);
  k_ln1_inproj<<<96, 256, 0, stream>>>(xp, ln1_g, ln1_b, in_proj_w, xc, z_t);
  k_dwconv<<<768, 256, 0, stream>>>(xc, dwconv_w, dwconv_b, xconv);
  k_xproj<<<576, 256, 0, stream>>>(xconv, x_proj_w, t36);
  k_dt<<<768, dim3(64,4), 0, stream>>>(t36, dt_proj_w, dt_proj_b, dts);
  k_scan_part<<<3072, 256, 0, stream>>>(dts, xconv, t36, A_logs, hend, prodA);
  k_scan_fix<<<192, 256, 0, stream>>>(hend, prodA, Hin);
  k_scan_y<<<3072, 256, 0, stream>>>(dts, xconv, t36, A_logs, Ds, Hin, ys);
  k_combine<<<1536, 256, 0, stream>>>(ys, z_t, out_norm_g, out_norm_b, yf);
  k_outproj<<<384, 256, 0, stream>>>(yf, x_cmaj, out_proj_w, xv);
  k_mlp<<<96, 256, 0, stream>>>(xv, ln2_g, ln2_b, fc1_w, fc1_b, fc2_w, fc2_b, (float*)d_out);
}

// Round 3
// 380.472 us; speedup vs baseline: 2.1080x; 1.6411x over previous
//
#include <hip/hip_runtime.h>
#include <math.h>

// Problem dims
#define BL    6
#define CCH   64
#define C3    192
#define L2    1024
#define DIC   128
#define NST   16
#define K4    4
#define PSTR  1088   // padded plane stride: 34 rows * 32 cols

#define LOG2E 1.44269504088896340736f
#define LN2C  0.69314718055994530942f

__device__ __forceinline__ float fexp(float x){ return __builtin_amdgcn_exp2f(x*LOG2E); }
__device__ __forceinline__ float fsilu(float x){ return x / (1.f + fexp(-x)); }
__device__ __forceinline__ float fsoftplus(float x){
  if (x > 20.f) return x;
  return __builtin_amdgcn_logf(1.f + fexp(x)) * LN2C;
}
__device__ __forceinline__ float fgelu(float x){
  return 0.5f*x*(1.f + erff(x*0.70710678118654752440f));
}

// ---------------- A: per-pixel channel LayerNorm of frames + concat [dz, frames_n, sigma]
// 96 blocks: (s, 16 px-groups of 64). threads = 64 px * 4 ch-groups of 16.
__global__ __launch_bounds__(256) void k_ln2d(const float* __restrict__ img,
    const float* __restrict__ dz, const float* __restrict__ sg,
    const float* __restrict__ g, const float* __restrict__ b, float* __restrict__ x3c){
  __shared__ float ps[4][64], pq[4][64];
  int s = blockIdx.x >> 4;
  int lane = threadIdx.x & 63;
  int cg = threadIdx.x >> 6;
  int p = ((blockIdx.x & 15) << 6) + lane;
  int bsmp = s/3;
  const float* fr = img + (size_t)s*CCH*L2;
  float vals[16]; float sm=0.f, sq=0.f;
  #pragma unroll
  for (int j=0;j<16;++j){
    int c = cg*16+j;
    float v = fr[c*L2+p];
    vals[j]=v; sm+=v; sq+=v*v;
  }
  ps[cg][lane]=sm; pq[cg][lane]=sq;
  __syncthreads();
  sm = ps[0][lane]+ps[1][lane]+ps[2][lane]+ps[3][lane];
  sq = pq[0][lane]+pq[1][lane]+pq[2][lane]+pq[3][lane];
  float mean = sm*(1.f/CCH); float var = sq*(1.f/CCH) - mean*mean;
  float rs = rsqrtf(var + 1e-6f);
  float* o = x3c + (size_t)s*C3*L2;
  const float* dzp = dz + (size_t)bsmp*CCH*L2;
  const float* sgp = sg + (size_t)bsmp*CCH*L2;
  #pragma unroll
  for (int j=0;j<16;++j){
    int c = cg*16+j;
    o[c*L2+p] = dzp[c*L2+p];
    o[(CCH+c)*L2+p] = (vals[j]-mean)*rs*g[c] + b[c];
    o[(2*CCH+c)*L2+p] = sgp[c*L2+p];
  }
}

// ---------------- GroupNorm(1) stats: 2-stage
__global__ __launch_bounds__(256) void k_gnstats_part(const float* __restrict__ x,
    int elems_per_s, float* __restrict__ psum, float* __restrict__ psq){
  int s = blockIdx.x >> 4; int i = blockIdx.x & 15;
  int chunk = elems_per_s >> 4;
  int tid = threadIdx.x;
  const float* xs = x + (size_t)s*elems_per_s + (size_t)i*chunk;
  float sm=0.f, sq=0.f;
  for (int idx = tid*4; idx < chunk; idx += 1024){
    float4 v = *(const float4*)(xs+idx);
    sm += v.x+v.y+v.z+v.w;
    sq += v.x*v.x+v.y*v.y+v.z*v.z+v.w*v.w;
  }
  for (int m=1;m<64;m<<=1){ sm+=__shfl_xor(sm,m,64); sq+=__shfl_xor(sq,m,64); }
  __shared__ float s_sm[4], s_sq[4];
  int wv = tid>>6;
  if ((tid&63)==0){ s_sm[wv]=sm; s_sq[wv]=sq; }
  __syncthreads();
  if (tid==0){
    psum[s*16+i] = s_sm[0]+s_sm[1]+s_sm[2]+s_sm[3];
    psq [s*16+i] = s_sq[0]+s_sq[1]+s_sq[2]+s_sq[3];
  }
}

__global__ __launch_bounds__(64) void k_gnstats_final(const float* __restrict__ psum,
    const float* __restrict__ psq, int elems_per_s, float eps, float* __restrict__ stats){
  int s = blockIdx.x; int lane = threadIdx.x;
  float sm = lane<16 ? psum[s*16+lane] : 0.f;
  float sq = lane<16 ? psq [s*16+lane] : 0.f;
  for (int m=1;m<16;m<<=1){ sm+=__shfl_xor(sm,m,64); sq+=__shfl_xor(sq,m,64); }
  if (lane==0){
    float mean = sm/elems_per_s; float var = sq/elems_per_s - mean*mean;
    stats[s*2] = mean; stats[s*2+1] = rsqrtf(var+eps);
  }
}

// ---------------- apply GN affine + SiLU, write PADDED plane (zero pad rows)
__global__ __launch_bounds__(256) void k_gnact_pad(const float* __restrict__ x,
    const float* __restrict__ stats, const float* __restrict__ g, const float* __restrict__ b,
    int ch, float* __restrict__ out){
  int bx = blockIdx.x;
  int s = bx / ch; int c = bx % ch;
  int tid = threadIdx.x;
  float mean = stats[s*2], rs = stats[s*2+1];
  float gc = g[c]*rs; float bc = b[c] - mean*rs*g[c];
  float4 v = *(const float4*)(x + (size_t)bx*1024 + tid*4);
  float4 o; o.x = fsilu(v.x*gc+bc); o.y = fsilu(v.y*gc+bc);
  o.z = fsilu(v.z*gc+bc); o.w = fsilu(v.w*gc+bc);
  float* pl = out + (size_t)bx*PSTR;
  *(float4*)(pl + 32 + tid*4) = o;
  float4 z4 = make_float4(0.f,0.f,0.f,0.f);
  if (tid < 8)  *(float4*)(pl + tid*4) = z4;                  // top pad row
  else if (tid < 16) *(float4*)(pl + 1056 + (tid-8)*4) = z4;  // bottom pad row
}

// conv row helper: accumulate 3 taps for 2 output channels over a 4-px quad
__device__ __forceinline__ void conv_row_acc(float4& a0, float4& a1, float4 mid, float lf, float rt,
    const float* wp0, const float* wp1){
  float w0=wp0[0], w1=wp0[1], w2=wp0[2];
  a0.x = fmaf(w0,lf,   fmaf(w1,mid.x, fmaf(w2,mid.y, a0.x)));
  a0.y = fmaf(w0,mid.x,fmaf(w1,mid.y, fmaf(w2,mid.z, a0.y)));
  a0.z = fmaf(w0,mid.y,fmaf(w1,mid.z, fmaf(w2,mid.w, a0.z)));
  a0.w = fmaf(w0,mid.z,fmaf(w1,mid.w, fmaf(w2,rt,    a0.w)));
  float v0=wp1[0], v1=wp1[1], v2=wp1[2];
  a1.x = fmaf(v0,lf,   fmaf(v1,mid.x, fmaf(v2,mid.y, a1.x)));
  a1.y = fmaf(v0,mid.x,fmaf(v1,mid.y, fmaf(v2,mid.z, a1.y)));
  a1.z = fmaf(v0,mid.y,fmaf(v1,mid.z, fmaf(v2,mid.w, a1.z)));
  a1.w = fmaf(v0,mid.z,fmaf(v1,mid.w, fmaf(v2,rt,    a1.w)));
}

// 3 rows of one padded plane, with prefetch regs
__device__ __forceinline__ void conv_ci_body(float4 m0, float4 m1, float4 m2, int q,
    const float* wp0, const float* wp1, float4& a0, float4& a1){
  float lf0=__shfl_up(m0.w,1,64), rt0=__shfl_down(m0.x,1,64);
  float lf1=__shfl_up(m1.w,1,64), rt1=__shfl_down(m1.x,1,64);
  float lf2=__shfl_up(m2.w,1,64), rt2=__shfl_down(m2.x,1,64);
  if (q==0){ lf0=0.f; lf1=0.f; lf2=0.f; }
  if (q==7){ rt0=0.f; rt1=0.f; rt2=0.f; }
  conv_row_acc(a0,a1,m0,lf0,rt0, wp0+0, wp1+0);
  conv_row_acc(a0,a1,m1,lf1,rt1, wp0+3, wp1+3);
  conv_row_acc(a0,a1,m2,lf2,rt2, wp0+6, wp1+6);
}

// ---------------- conv1: 192ci -> 64co, split-K=4 (48 ci each), padded input
__global__ __launch_bounds__(256) void k_conv1_split(const float* __restrict__ xact,
    const float* __restrict__ w, float* __restrict__ part){
  int bx = blockIdx.x; int kk = bx&3; int cop=(bx>>2)&31; int s=bx>>7;
  int co0 = cop*2, co1 = co0+1;
  int tid = threadIdx.x; int row = tid>>3; int q = tid&7; int col0 = q*4;
  float4 a0 = make_float4(0.f,0.f,0.f,0.f);
  float4 a1 = make_float4(0.f,0.f,0.f,0.f);
  int ci0 = kk*48;
  const float* pl = xact + ((size_t)s*C3 + ci0)*PSTR + row*32 + col0;
  const float* wp0 = w + (size_t)(co0*C3 + ci0)*9;
  const float* wp1 = w + (size_t)(co1*C3 + ci0)*9;
  float4 m0 = *(const float4*)(pl);
  float4 m1 = *(const float4*)(pl+32);
  float4 m2 = *(const float4*)(pl+64);
  #pragma unroll 2
  for (int i=0;i<48;++i){
    const float* pn = pl + (i<47 ? PSTR : 0);
    float4 n0 = *(const float4*)(pn);
    float4 n1 = *(const float4*)(pn+32);
    float4 n2 = *(const float4*)(pn+64);
    conv_ci_body(m0,m1,m2,q, wp0, wp1, a0, a1);
    wp0 += 9; wp1 += 9; pl = pn; m0=n0; m1=n1; m2=n2;
  }
  float* pp = part + (size_t)kk*(BL*CCH*L2) + ((size_t)s*CCH+co0)*L2 + row*32+col0;
  *(float4*)pp = a0;
  *(float4*)(pp+L2) = a1;
}

// reduce 4 partials + bias -> h1
__global__ __launch_bounds__(256) void k_reduce1(const float* __restrict__ part,
    const float* __restrict__ bias, float* __restrict__ h1){
  int co = blockIdx.x & 63; int s = blockIdx.x >> 6;
  size_t ofs = ((size_t)s*CCH+co)*L2 + threadIdx.x*4;
  const size_t stride = (size_t)BL*CCH*L2;
  float4 r0 = *(const float4*)(part + ofs);
  float4 r1 = *(const float4*)(part + stride + ofs);
  float4 r2 = *(const float4*)(part + 2*stride + ofs);
  float4 r3 = *(const float4*)(part + 3*stride + ofs);
  float bv = bias[co];
  float4 o;
  o.x = r0.x+r1.x+r2.x+r3.x+bv;
  o.y = r0.y+r1.y+r2.y+r3.y+bv;
  o.z = r0.z+r1.z+r2.z+r3.z+bv;
  o.w = r0.w+r1.w+r2.w+r3.w+bv;
  *(float4*)(h1 + ofs) = o;
}

// ---------------- conv2 3x3 (64ci, padded, roles 0/1 = 32ci each) + skip 1x1 (role 2)
__global__ __launch_bounds__(256) void k_conv2_split(const float* __restrict__ xact2,
    const float* __restrict__ x3c, const float* __restrict__ w2,
    const float* __restrict__ wsk, float* __restrict__ part){
  int t = blockIdx.x; int role = t % 3; t /= 3;
  int cop = t & 31; int s = t >> 5;
  int co0 = cop*2, co1 = co0+1;
  int tid = threadIdx.x; int row = tid>>3; int q = tid&7; int col0 = q*4;
  int p = row*32+col0;
  float4 a0 = make_float4(0.f,0.f,0.f,0.f);
  float4 a1 = make_float4(0.f,0.f,0.f,0.f);
  if (role < 2){
    int ci0 = role*32;
    const float* pl = xact2 + ((size_t)s*CCH + ci0)*PSTR + row*32 + col0;
    const float* wp0 = w2 + (size_t)(co0*CCH + ci0)*9;
    const float* wp1 = w2 + (size_t)(co1*CCH + ci0)*9;
    float4 m0 = *(const float4*)(pl);
    float4 m1 = *(const float4*)(pl+32);
    float4 m2 = *(const float4*)(pl+64);
    #pragma unroll 2
    for (int i=0;i<32;++i){
      const float* pn = pl + (i<31 ? PSTR : 0);
      float4 n0 = *(const float4*)(pn);
      float4 n1 = *(const float4*)(pn+32);
      float4 n2 = *(const float4*)(pn+64);
      conv_ci_body(m0,m1,m2,q, wp0, wp1, a0, a1);
      wp0 += 9; wp1 += 9; pl = pn; m0=n0; m1=n1; m2=n2;
    }
  } else {
    const float* x3 = x3c + (size_t)s*C3*L2 + p;
    #pragma unroll 4
    for (int ci=0; ci<C3; ++ci){
      float4 v = *(const float4*)(x3 + (size_t)ci*L2);
      float ws0 = wsk[co0*C3+ci], ws1 = wsk[co1*C3+ci];
      a0.x = fmaf(ws0,v.x,a0.x); a0.y = fmaf(ws0,v.y,a0.y); a0.z = fmaf(ws0,v.z,a0.z); a0.w = fmaf(ws0,v.w,a0.w);
      a1.x = fmaf(ws1,v.x,a1.x); a1.y = fmaf(ws1,v.y,a1.y); a1.z = fmaf(ws1,v.z,a1.z); a1.w = fmaf(ws1,v.w,a1.w);
    }
  }
  float* pp = part + (size_t)role*(BL*CCH*L2) + ((size_t)s*CCH+co0)*L2 + p;
  *(float4*)pp = a0;
  *(float4*)(pp+L2) = a1;
}

// reduce 3 partials + biases -> x_cmaj and xp (px-major)
__global__ __launch_bounds__(256) void k_reduce2(const float* __restrict__ part,
    const float* __restrict__ b2, const float* __restrict__ bsk,
    float* __restrict__ xp, float* __restrict__ x_cmaj){
  int co = blockIdx.x & 63; int s = blockIdx.x >> 6;
  int p = threadIdx.x*4;
  size_t ofs = ((size_t)s*CCH+co)*L2 + p;
  const size_t stride = (size_t)BL*CCH*L2;
  float4 r0 = *(const float4*)(part + ofs);
  float4 r1 = *(const float4*)(part + stride + ofs);
  float4 r2 = *(const float4*)(part + 2*stride + ofs);
  float bv = b2[co]+bsk[co];
  float4 o;
  o.x = r0.x+r1.x+r2.x+bv;
  o.y = r0.y+r1.y+r2.y+bv;
  o.z = r0.z+r1.z+r2.z+bv;
  o.w = r0.w+r1.w+r2.w+bv;
  *(float4*)(x_cmaj + ofs) = o;
  float* xpb = xp + ((size_t)s*L2 + p)*CCH + co;
  xpb[0] = o.x; xpb[CCH] = o.y; xpb[2*CCH] = o.z; xpb[3*CCH] = o.w;
}

// ---------------- H: ln1 + in_proj (256 outputs); split into xc (c-major) and z (c-major)
__global__ __launch_bounds__(256) void k_ln1_inproj(const float* __restrict__ xp,
    const float* __restrict__ g, const float* __restrict__ b, const float* __restrict__ W,
    float* __restrict__ xc, float* __restrict__ z_t){
  __shared__ float xn_s[64*65];
  int s = blockIdx.x >> 4; int p0 = (blockIdx.x & 15)*64;
  int tid = threadIdx.x; int wv = __builtin_amdgcn_readfirstlane(tid>>6); int lane = tid&63;
  for (int j=0;j<16;++j){
    int pl = wv*16 + j; int p = p0 + pl;
    float v = xp[((size_t)s*L2 + p)*CCH + lane];
    float sm = v, sq = v*v;
    for (int m=1;m<64;m<<=1){ sm += __shfl_xor(sm,m,64); sq += __shfl_xor(sq,m,64); }
    float mean = sm*(1.f/64.f); float var = sq*(1.f/64.f) - mean*mean;
    float rs = rsqrtf(var + 1e-5f);
    xn_s[pl*65 + lane] = (v-mean)*rs*g[lane] + b[lane];
  }
  __syncthreads();
  int px_l = tid & 63;
  int og = __builtin_amdgcn_readfirstlane(tid >> 6);
  int o0 = og*64;
  float acc[64];
  #pragma unroll
  for (int oi=0;oi<64;++oi) acc[oi]=0.f;
  for (int c=0;c<64;++c){
    float xv = xn_s[px_l*65 + c];
    #pragma unroll
    for (int oi=0;oi<64;++oi) acc[oi] = fmaf(W[(o0+oi)*64 + c], xv, acc[oi]);
  }
  int p = p0 + px_l;
  if (og < 2){
    #pragma unroll
    for (int oi=0;oi<64;++oi) xc[((size_t)s*DIC + o0 + oi)*L2 + p] = acc[oi];
  } else {
    #pragma unroll
    for (int oi=0;oi<64;++oi) z_t[((size_t)s*DIC + (o0-128) + oi)*L2 + p] = acc[oi];
  }
}

// ---------------- I: depthwise 3x3 conv + bias + SiLU
__global__ __launch_bounds__(256) void k_dwconv(const float* __restrict__ xc,
    const float* __restrict__ w, const float* __restrict__ bias, float* __restrict__ xconv){
  int bx = blockIdx.x; int dch = bx & 127; int s = bx >> 7;
  int tid = threadIdx.x; int row = tid>>3; int q = tid&7; int col0 = q*4;
  const float* xr = xc + ((size_t)s*DIC+dch)*L2;
  const float* wp = w + dch*9;
  float bv = bias[dch];
  float4 acc = make_float4(bv,bv,bv,bv);
  #pragma unroll
  for (int dy=-1;dy<=1;++dy){
    int r = row+dy;
    float4 mid = make_float4(0.f,0.f,0.f,0.f);
    if (0<=r && r<32) mid = *(const float4*)(xr + r*32 + col0);
    float lf = __shfl_up(mid.w,1,64); if(q==0) lf=0.f;
    float rt = __shfl_down(mid.x,1,64); if(q==7) rt=0.f;
    float w0=wp[(dy+1)*3], w1=wp[(dy+1)*3+1], w2=wp[(dy+1)*3+2];
    acc.x = fmaf(w0,lf,   fmaf(w1,mid.x, fmaf(w2,mid.y, acc.x)));
    acc.y = fmaf(w0,mid.x,fmaf(w1,mid.y, fmaf(w2,mid.z, acc.y)));
    acc.z = fmaf(w0,mid.y,fmaf(w1,mid.z, fmaf(w2,mid.w, acc.z)));
    acc.w = fmaf(w0,mid.z,fmaf(w1,mid.w, fmaf(w2,rt,    acc.w)));
  }
  acc.x = fsilu(acc.x); acc.y = fsilu(acc.y); acc.z = fsilu(acc.z); acc.w = fsilu(acc.w);
  *(float4*)(xconv + ((size_t)s*DIC+dch)*L2 + row*32+col0) = acc;
}

// ---------------- J: x_proj: t36[s,k,c,p] = sum_d Xw[k,c,d]*xconv[s,d,p] (pixel order)
__global__ __launch_bounds__(256) void k_xproj(const float* __restrict__ xconv,
    const float* __restrict__ W, float* __restrict__ t36){
  int bx = blockIdx.x;
  int pg = bx & 3; int t = bx >> 2;
  int cg = t % 6; int t2 = t / 6;
  int k = t2 & 3; int s = t2 >> 2;
  int px = pg*256 + threadIdx.x;
  const float* xb = xconv + (size_t)s*DIC*L2 + px;
  const float* wb = W + (size_t)(k*36 + cg*6)*DIC;
  float acc[6] = {0.f,0.f,0.f,0.f,0.f,0.f};
  for (int dch=0; dch<DIC; ++dch){
    float v = xb[(size_t)dch*L2];
    #pragma unroll
    for (int ci=0; ci<6; ++ci) acc[ci] = fmaf(wb[ci*DIC+dch], v, acc[ci]);
  }
  float* ob = t36 + ((size_t)(s*4+k)*36 + cg*6)*L2 + px;
  #pragma unroll
  for (int ci=0;ci<6;++ci) ob[(size_t)ci*L2] = acc[ci];
}

// ---------------- K: dt = softplus(dt_proj(t36[0:4]) + bias), pixel order
__global__ void k_dt(const float* __restrict__ t36, const float* __restrict__ dtw,
    const float* __restrict__ dtb, float* __restrict__ dts){
  int dgrp = blockIdx.x & 31; int k = (blockIdx.x>>5)&3; int s = blockIdx.x>>7;
  int lane = threadIdx.x;
  int dl = __builtin_amdgcn_readfirstlane(threadIdx.y);
  int dch = dgrp*4 + dl;
  const float* tb = t36 + (size_t)(s*4+k)*36*L2;
  float w0 = dtw[(k*DIC+dch)*4+0], w1 = dtw[(k*DIC+dch)*4+1];
  float w2 = dtw[(k*DIC+dch)*4+2], w3 = dtw[(k*DIC+dch)*4+3];
  float bb = dtb[k*DIC+dch];
  float* ob = dts + ((size_t)(s*4+k)*DIC + dch)*L2;
  for (int pg=0; pg<4; ++pg){
    int px = (pg*64 + lane)*4;
    float4 r0 = *(const float4*)(tb + 0*L2 + px);
    float4 r1 = *(const float4*)(tb + 1*L2 + px);
    float4 r2 = *(const float4*)(tb + 2*L2 + px);
    float4 r3 = *(const float4*)(tb + 3*L2 + px);
    float4 o;
    o.x = fsoftplus(fmaf(w0,r0.x,fmaf(w1,r1.x,fmaf(w2,r2.x,fmaf(w3,r3.x,bb)))));
    o.y = fsoftplus(fmaf(w0,r0.y,fmaf(w1,r1.y,fmaf(w2,r2.y,fmaf(w3,r3.y,bb)))));
    o.z = fsoftplus(fmaf(w0,r0.z,fmaf(w1,r1.z,fmaf(w2,r2.z,fmaf(w3,r3.z,bb)))));
    o.w = fsoftplus(fmaf(w0,r0.w,fmaf(w1,r1.w,fmaf(w2,r2.w,fmaf(w3,r3.w,bb)))));
    *(float4*)(ob+px) = o;
  }
}

// ======== Selective scan: 2-pass chunked parallel scan (16 chunks of 64 steps) ========
__device__ __forceinline__ float4 scan_load4(const float* __restrict__ rowp, int ib, int k){
  if (k==0){ return *(const float4*)(rowp + ib); }
  else if (k==2){
    float4 t = *(const float4*)(rowp + (1020 - ib));
    return make_float4(t.w, t.z, t.y, t.x);
  } else if (k==1){
    int p0 = ((ib&31)<<5) | (ib>>5);
    return make_float4(rowp[p0], rowp[p0+32], rowp[p0+64], rowp[p0+96]);
  } else {
    int idx = 1023 - ib;
    int p0 = ((idx&31)<<5) | (idx>>5);
    return make_float4(rowp[p0], rowp[p0-32], rowp[p0-64], rowp[p0-96]);
  }
}

__global__ __launch_bounds__(256) void k_scan_part(const float* __restrict__ dts,
    const float* __restrict__ xconv, const float* __restrict__ t36,
    const float* __restrict__ A_logs, float* __restrict__ hend, float* __restrict__ prodA){
  const int P = 68;
  int bx = blockIdx.x; int ch = bx & 15; int dg = (bx>>4)&7; int k = (bx>>7)&3; int s = bx>>9;
  int tid = threadIdx.x; int n = tid & 15; int dl = tid >> 4;
  int d = dg*16 + dl;
  __shared__ float dt_s[16*P], u_s[16*P], B_s[16*P];
  float expA = fexp(A_logs[(k*DIC+d)*NST + n]);
  float aco = -expA * LOG2E;
  int r_st = tid >> 4; int i_st = (tid & 15) << 2;
  const float* dtrow = dts   + ((size_t)(s*4+k)*DIC + dg*16 + r_st)*L2;
  const float* urow  = xconv + ((size_t)s*DIC + dg*16 + r_st)*L2;
  const float* Brow  = t36   + ((size_t)(s*4+k)*36 + 4 + r_st)*L2;
  int ib = ch*64 + i_st;
  int wofs = r_st*P + i_st;
  *(float4*)&dt_s[wofs] = scan_load4(dtrow, ib, k);
  *(float4*)&u_s[wofs]  = scan_load4(urow,  ib, k);
  *(float4*)&B_s[wofs]  = scan_load4(Brow,  ib, k);
  __syncthreads();
  const float* dtp = &dt_s[dl*P];
  const float* up  = &u_s[dl*P];
  const float* Bp  = &B_s[n*P];
  float h = 0.f, Pr = 1.f;
  #pragma unroll 4
  for (int ii=0; ii<64; ii+=4){
    float4 dt4 = *(const float4*)(dtp+ii);
    float4 u4  = *(const float4*)(up+ii);
    float4 B4  = *(const float4*)(Bp+ii);
    #define PART_STEP(DT,U,BV) { \
      float a_ = __builtin_amdgcn_exp2f((DT)*aco); \
      h = fmaf(a_, h, (DT)*(U)*(BV)); \
      Pr *= a_; }
    PART_STEP(dt4.x,u4.x,B4.x)
    PART_STEP(dt4.y,u4.y,B4.y)
    PART_STEP(dt4.z,u4.z,B4.z)
    PART_STEP(dt4.w,u4.w,B4.w)
    #undef PART_STEP
  }
  size_t seq = (size_t)(s*4+k)*DIC + d;
  hend [(seq*16+n)*16 + ch] = h;
  prodA[(seq*16+n)*16 + ch] = Pr;
}

__global__ __launch_bounds__(256) void k_scan_fix(const float* __restrict__ hend,
    const float* __restrict__ prodA, float* __restrict__ Hin){
  int t = blockIdx.x*256 + threadIdx.x;
  const float* he = hend  + (size_t)t*16;
  const float* pa = prodA + (size_t)t*16;
  float* hi = Hin + (size_t)t*16;
  float H = 0.f;
  #pragma unroll
  for (int c=0;c<16;++c){ hi[c] = H; H = fmaf(pa[c], H, he[c]); }
}

__global__ __launch_bounds__(256) void k_scan_y(const float* __restrict__ dts,
    const float* __restrict__ xconv, const float* __restrict__ t36,
    const float* __restrict__ A_logs, const float* __restrict__ Ds,
    const float* __restrict__ Hin, float* __restrict__ ys){
  const int P = 68;
  int bx = blockIdx.x; int ch = bx & 15; int dg = (bx>>4)&7; int k = (bx>>7)&3; int s = bx>>9;
  int tid = threadIdx.x; int n = tid & 15; int dl = tid >> 4;
  int d = dg*16 + dl;
  __shared__ float dt_s[16*P], u_s[16*P], B_s[16*P], C_s[16*P];
  __shared__ float y_s[16*P];
  float expA = fexp(A_logs[(k*DIC+d)*NST + n]);
  float aco = -expA * LOG2E;
  float Dv = Ds[k*DIC+d];
  int r_st = tid >> 4; int i_st = (tid & 15) << 2;
  const float* dtrow = dts   + ((size_t)(s*4+k)*DIC + dg*16 + r_st)*L2;
  const float* urow  = xconv + ((size_t)s*DIC + dg*16 + r_st)*L2;
  const float* Brow  = t36   + ((size_t)(s*4+k)*36 + 4 + r_st)*L2;
  const float* Crow  = t36   + ((size_t)(s*4+k)*36 + 20 + r_st)*L2;
  int ib = ch*64 + i_st;
  int wofs = r_st*P + i_st;
  *(float4*)&dt_s[wofs] = scan_load4(dtrow, ib, k);
  *(float4*)&u_s[wofs]  = scan_load4(urow,  ib, k);
  *(float4*)&B_s[wofs]  = scan_load4(Brow,  ib, k);
  *(float4*)&C_s[wofs]  = scan_load4(Crow,  ib, k);
  size_t seq = (size_t)(s*4+k)*DIC + d;
  float h = Hin[(seq*16+n)*16 + ch];
  __syncthreads();
  const float* dtp = &dt_s[dl*P];
  const float* up  = &u_s[dl*P];
  const float* Bp  = &B_s[n*P];
  const float* Cp  = &C_s[n*P];
  #pragma unroll 4
  for (int ii=0; ii<64; ii+=4){
    float4 dt4 = *(const float4*)(dtp+ii);
    float4 u4  = *(const float4*)(up+ii);
    float4 B4  = *(const float4*)(Bp+ii);
    float4 C4  = *(const float4*)(Cp+ii);
    #define SCAN_STEP(DT,U,BV,CV,IDX) { \
      float a_ = __builtin_amdgcn_exp2f((DT)*aco); \
      h = fmaf(a_, h, (DT)*(U)*(BV)); \
      float v_ = h*(CV); \
      v_ += __shfl_xor(v_,1,64); v_ += __shfl_xor(v_,2,64); \
      v_ += __shfl_xor(v_,4,64); v_ += __shfl_xor(v_,8,64); \
      if (n==0) y_s[dl*P + (IDX)] = fmaf((U), Dv, v_); }
    SCAN_STEP(dt4.x,u4.x,B4.x,C4.x, ii+0)
    SCAN_STEP(dt4.y,u4.y,B4.y,C4.y, ii+1)
    SCAN_STEP(dt4.z,u4.z,B4.z,C4.z, ii+2)
    SCAN_STEP(dt4.w,u4.w,B4.w,C4.w, ii+3)
    #undef SCAN_STEP
  }
  __syncthreads();
  float4 yv = *(float4*)&y_s[r_st*P + i_st];
  float* ysblk = ys + ((size_t)(s*4+k)*DIC + dg*16)*L2;
  *(float4*)(ysblk + (size_t)r_st*L2 + ch*64 + i_st) = yv;
}

// ---------------- M1: combine 4 directions + out_norm LN(128) + *silu(z) -> yf (c-major)
__global__ __launch_bounds__(256) void k_combine(const float* __restrict__ ys,
    const float* __restrict__ z_t, const float* __restrict__ g, const float* __restrict__ b,
    float* __restrict__ yf){
  int wv = __builtin_amdgcn_readfirstlane(threadIdx.x>>6); int lane = threadIdx.x&63;
  int gp = blockIdx.x*4 + wv; int s = gp>>10; int p = gp&1023;
  int tp = ((p&31)<<5) | (p>>5);
  const float* yb = ys + (size_t)s*4*DIC*L2;
  int d0 = lane, d1 = lane+64;
  float ya = yb[(size_t)(0*DIC+d0)*L2 + p] + yb[(size_t)(2*DIC+d0)*L2 + (1023-p)]
           + yb[(size_t)(1*DIC+d0)*L2 + tp] + yb[(size_t)(3*DIC+d0)*L2 + (1023-tp)];
  float yc = yb[(size_t)(0*DIC+d1)*L2 + p] + yb[(size_t)(2*DIC+d1)*L2 + (1023-p)]
           + yb[(size_t)(1*DIC+d1)*L2 + tp] + yb[(size_t)(3*DIC+d1)*L2 + (1023-tp)];
  float sm = ya+yc, sq = ya*ya+yc*yc;
  for (int m=1;m<64;m<<=1){ sm+=__shfl_xor(sm,m,64); sq+=__shfl_xor(sq,m,64); }
  float mean = sm*(1.f/128.f); float var = sq*(1.f/128.f)-mean*mean;
  float rs = rsqrtf(var + 1e-5f);
  float yn0 = (ya-mean)*rs*g[d0] + b[d0];
  float yn1 = (yc-mean)*rs*g[d1] + b[d1];
  float zv0 = z_t[((size_t)s*DIC+d0)*L2 + p];
  float zv1 = z_t[((size_t)s*DIC+d1)*L2 + p];
  yf[((size_t)s*DIC+d0)*L2 + p] = yn0 * fsilu(zv0);
  yf[((size_t)s*DIC+d1)*L2 + p] = yn1 * fsilu(zv1);
}

// ---------------- M2a: xv = x + yf @ out_proj^T (c-major)
__global__ __launch_bounds__(256) void k_outproj(const float* __restrict__ yf,
    const float* __restrict__ x_cmaj, const float* __restrict__ W, float* __restrict__ xv){
  int bx = blockIdx.x; int cb = bx&3; int pg=(bx>>2)&15; int s=bx>>6;
  int lane = threadIdx.x&63;
  int cq = __builtin_amdgcn_readfirstlane(threadIdx.x>>6);
  int px = pg*64 + lane; int c0 = cb*16 + cq*4;
  const float* yb = yf + (size_t)s*DIC*L2 + px;
  float a0=0.f,a1=0.f,a2=0.f,a3=0.f;
  for (int dch=0;dch<DIC;++dch){
    float v = yb[(size_t)dch*L2];
    a0 = fmaf(W[(c0+0)*DIC+dch], v, a0);
    a1 = fmaf(W[(c0+1)*DIC+dch], v, a1);
    a2 = fmaf(W[(c0+2)*DIC+dch], v, a2);
    a3 = fmaf(W[(c0+3)*DIC+dch], v, a3);
  }
  size_t base = ((size_t)s*CCH+c0)*L2 + px;
  xv[base]        = x_cmaj[base]        + a0;
  xv[base+L2]     = x_cmaj[base+L2]     + a1;
  xv[base+2*L2]   = x_cmaj[base+2*L2]   + a2;
  xv[base+3*L2]   = x_cmaj[base+3*L2]   + a3;
}

// ---------------- M2b: ln2 + fc1 + gelu + fc2 + residual -> output (c-major)
__global__ __launch_bounds__(256) void k_mlp(const float* __restrict__ xv_in,
    const float* __restrict__ g, const float* __restrict__ b,
    const float* __restrict__ w1, const float* __restrict__ b1,
    const float* __restrict__ w2, const float* __restrict__ b2, float* __restrict__ out){
  __shared__ float xt[64*65];
  __shared__ float ts[64*65];
  int s = blockIdx.x >> 4; int p0 = (blockIdx.x & 15)*64;
  int tid = threadIdx.x; int lane = tid & 63;
  int grp = __builtin_amdgcn_readfirstlane(tid >> 6);
  for (int j=0;j<16;++j){
    int c = grp*16 + j;
    xt[c*65 + lane] = xv_in[((size_t)s*CCH + c)*L2 + p0 + lane];
  }
  __syncthreads();
  float sm=0.f, sq=0.f;
  for (int c=0;c<64;++c){ float v = xt[c*65+lane]; sm+=v; sq+=v*v; }
  float mean = sm*(1.f/64.f);
  float rs = rsqrtf(sq*(1.f/64.f) - mean*mean + 1e-5f);
  int o0 = grp*16;
  float t[16];
  #pragma unroll
  for (int oi=0;oi<16;++oi) t[oi] = b1[o0+oi];
  for (int c=0;c<64;++c){
    float xn = (xt[c*65+lane]-mean)*rs*g[c] + b[c];
    #pragma unroll
    for (int oi=0;oi<16;++oi) t[oi] = fmaf(xn, w1[(o0+oi)*64 + c], t[oi]);
  }
  #pragma unroll
  for (int oi=0;oi<16;++oi) ts[lane*65 + o0+oi] = fgelu(t[oi]);
  __syncthreads();
  int c0 = grp*16;
  float acc[16];
  #pragma unroll
  for (int ci=0;ci<16;++ci) acc[ci] = xt[(c0+ci)*65+lane] + b2[c0+ci];
  for (int o=0;o<64;++o){
    float tv = ts[lane*65 + o];
    #pragma unroll
    for (int ci=0;ci<16;++ci) acc[ci] = fmaf(tv, w2[(c0+ci)*64 + o], acc[ci]);
  }
  #pragma unroll
  for (int ci=0;ci<16;++ci) out[((size_t)s*CCH + c0+ci)*L2 + p0 + lane] = acc[ci];
}

extern "C" void kernel_launch(void* const* d_in, const int* in_sizes, int n_in,
                              void* d_out, int out_size, void* d_ws, size_t ws_size,
                              hipStream_t stream){
  (void)in_sizes; (void)n_in; (void)out_size; (void)ws_size;
  const float* img      = (const float*)d_in[0];
  const float* dz       = (const float*)d_in[1];
  const float* sg       = (const float*)d_in[2];
  const float* norm_g   = (const float*)d_in[3];
  const float* norm_b   = (const float*)d_in[4];
  const float* gn1_g    = (const float*)d_in[5];
  const float* gn1_b    = (const float*)d_in[6];
  const float* conv1_w  = (const float*)d_in[7];
  const float* conv1_b  = (const float*)d_in[8];
  const float* gn2_g    = (const float*)d_in[9];
  const float* gn2_b    = (const float*)d_in[10];
  const float* conv2_w  = (const float*)d_in[11];
  const float* conv2_b  = (const float*)d_in[12];
  const float* skip_w   = (const float*)d_in[13];
  const float* skip_b   = (const float*)d_in[14];
  const float* ln1_g    = (const float*)d_in[15];
  const float* ln1_b    = (const float*)d_in[16];
  const float* ln2_g    = (const float*)d_in[17];
  const float* ln2_b    = (const float*)d_in[18];
  const float* in_proj_w= (const float*)d_in[19];
  const float* dwconv_w = (const float*)d_in[20];
  const float* dwconv_b = (const float*)d_in[21];
  const float* x_proj_w = (const float*)d_in[22];
  const float* dt_proj_w= (const float*)d_in[23];
  const float* dt_proj_b= (const float*)d_in[24];
  const float* A_logs   = (const float*)d_in[25];
  const float* Ds       = (const float*)d_in[26];
  const float* out_norm_g = (const float*)d_in[27];
  const float* out_norm_b = (const float*)d_in[28];
  const float* out_proj_w = (const float*)d_in[29];
  const float* fc1_w    = (const float*)d_in[30];
  const float* fc1_b    = (const float*)d_in[31];
  const float* fc2_w    = (const float*)d_in[32];
  const float* fc2_b    = (const float*)d_in[33];

  float* ws = (float*)d_ws;
  float* x3c    = ws;                       // 1,179,648
  float* xact1  = x3c    + 1179648;         // 1,253,376 (padded)
  float* h1     = xact1  + 1253376;         // 393,216
  float* xact2  = h1     + 393216;          // 417,792 (padded)
  float* xp     = xact2  + 417792;          // 393,216
  float* x_cmaj = xp     + 393216;          // 393,216
  float* z_t    = x_cmaj + 393216;          // 786,432
  float* xc     = z_t    + 786432;          // 786,432
  float* xconv  = xc     + 786432;          // 786,432
  float* t36    = xconv  + 786432;          // 884,736
  float* dts    = t36    + 884736;          // 3,145,728 (also hosts conv1 partials)
  float* ys     = dts    + 3145728;         // 3,145,728 (also hosts conv2 partials)
  float* yf     = ys     + 3145728;         // 786,432
  float* xv     = yf     + 786432;          // 393,216
  float* psum   = xv     + 393216;          // 96
  float* psq    = psum   + 96;              // 96
  float* stats1 = psq    + 96;              // 12
  float* stats2 = stats1 + 12;              // 12
  // conv partials (regions dead until later stages)
  float* part1  = dts;   // 4 * 393216
  float* part2  = ys;    // 3 * 393216
  // scan scratch reuses x3c+xact1 (dead after conv2_split)
  float* hend   = x3c;
  float* prodA  = x3c + 786432;
  float* Hin    = x3c + 1572864;

  k_ln2d<<<96, 256, 0, stream>>>(img, dz, sg, norm_g, norm_b, x3c);
  k_gnstats_part<<<96, 256, 0, stream>>>(x3c, C3*L2, psum, psq);
  k_gnstats_final<<<6, 64, 0, stream>>>(psum, psq, C3*L2, 1e-5f, stats1);
  k_gnact_pad<<<6*C3, 256, 0, stream>>>(x3c, stats1, gn1_g, gn1_b, C3, xact1);
  k_conv1_split<<<768, 256, 0, stream>>>(xact1, conv1_w, part1);
  k_reduce1<<<384, 256, 0, stream>>>(part1, conv1_b, h1);
  k_gnstats_part<<<96, 256, 0, stream>>>(h1, CCH*L2, psum, psq);
  k_gnstats_final<<<6, 64, 0, stream>>>(psum, psq, CCH*L2, 1e-5f, stats2);
  k_gnact_pad<<<6*CCH, 256, 0, stream>>>(h1, stats2, gn2_g, gn2_b, CCH, xact2);
  k_conv2_split<<<576, 256, 0, stream>>>(xact2, x3c, conv2_w, skip_w, part2);
  k_reduce2<<<384, 256, 0, stream>>>(part2, conv2_b, skip_b, xp, x_cmaj);
  k_ln1_inproj<<<96, 256, 0, stream>>>(xp, ln1_g, ln1_b, in_proj_w, xc, z_t);
  k_dwconv<<<768, 256, 0, stream>>>(xc, dwconv_w, dwconv_b, xconv);
  k_xproj<<<576, 256, 0, stream>>>(xconv, x_proj_w, t36);
  k_dt<<<768, dim3(64,4), 0, stream>>>(t36, dt_proj_w, dt_proj_b, dts);
  k_scan_part<<<3072, 256, 0, stream>>>(dts, xconv, t36, A_logs, hend, prodA);
  k_scan_fix<<<192, 256, 0, stream>>>(hend, prodA, Hin);
  k_scan_y<<<3072, 256, 0, stream>>>(dts, xconv, t36, A_logs, Ds, Hin, ys);
  k_combine<<<1536, 256, 0, stream>>>(ys, z_t, out_norm_g, out_norm_b, yf);
  k_outproj<<<384, 256, 0, stream>>>(yf, x_cmaj, out_proj_w, xv);
  k_mlp<<<96, 256, 0, stream>>>(xv, ln2_g, ln2_b, fc1_w, fc1_b, fc2_w, fc2_b, (float*)d_out);
}